// Round 6
// baseline (834.328 us; speedup 1.0000x reference)
//
#include <hip/hip_runtime.h>
#include <hip/hip_bf16.h>

#define BN_EPS 1e-5f
#define SCAN_CHUNK 2048  // 256 threads * 8 elems
#define BSH 6            // bucket = tgt >> 6 (64 nodes/bucket)
#define BUCKN 64

static inline int cdiv(long long a, long long b) { return (int)((a + b - 1) / b); }

__device__ __forceinline__ float bf2f(unsigned short u) {
    return __uint_as_float(((unsigned int)u) << 16);
}
__device__ __forceinline__ float lo16(int u) {
    return __uint_as_float(((unsigned int)u) << 16);
}
__device__ __forceinline__ float hi16(int u) {
    return __uint_as_float(((unsigned int)u) & 0xffff0000u);
}
__device__ __forceinline__ unsigned short f2bf(float f) {
    unsigned int b = __float_as_uint(f);
    b += 0x7FFFu + ((b >> 16) & 1u);  // RNE
    return (unsigned short)(b >> 16);
}

// ---------------- histogram ----------------
__global__ void k_hist(const int* __restrict__ idx, int* __restrict__ cnt, int n) {
    int i = blockIdx.x * blockDim.x + threadIdx.x;
    if (i < n) atomicAdd(&cnt[idx[i]], 1);
}

// ---------------- hierarchical scan: pass 1 (block sums) ----------------
__global__ __launch_bounds__(256) void k_scan_blk(const int* __restrict__ cnt,
                                                  int* __restrict__ bsum, int n) {
    const int t = threadIdx.x;
    const int base = blockIdx.x * SCAN_CHUNK + t * 8;
    int s = 0;
    if (base + 8 <= n) {
        int4 a = *(const int4*)(cnt + base);
        int4 b = *(const int4*)(cnt + base + 4);
        s = a.x + a.y + a.z + a.w + b.x + b.y + b.z + b.w;
    } else {
#pragma unroll
        for (int j = 0; j < 8; j++) {
            int i = base + j;
            if (i < n) s += cnt[i];
        }
    }
    __shared__ int red[256];
    red[t] = s;
    __syncthreads();
    for (int d = 128; d > 0; d >>= 1) {
        if (t < d) red[t] += red[t + d];
        __syncthreads();
    }
    if (t == 0) bsum[blockIdx.x] = red[0];
}

// ---------------- pass 2: scan of block sums (nb <= 256) ----------------
__global__ __launch_bounds__(256) void k_scan_bsum(int* __restrict__ bsum,
                                                   int* __restrict__ off, int nb, int n) {
    const int t = threadIdx.x;
    __shared__ int sh[256];
    int v = (t < nb) ? bsum[t] : 0;
    sh[t] = v;
    __syncthreads();
    for (int d = 1; d < 256; d <<= 1) {
        int u = (t >= d) ? sh[t - d] : 0;
        __syncthreads();
        sh[t] += u;
        __syncthreads();
    }
    if (t < nb) bsum[t] = sh[t] - v;  // exclusive block offset
    if (t == 255) off[n] = sh[255];   // grand total
}

// ---------------- pass 3: write exclusive offsets (+ optional dis/cursor) ----------------
__global__ __launch_bounds__(256) void k_scan_out(const int* __restrict__ cnt,
                                                  const int* __restrict__ bsum,
                                                  int* __restrict__ off, int n,
                                                  float* __restrict__ dis,
                                                  int* __restrict__ cursor) {
    const int t = threadIdx.x;
    const int base = blockIdx.x * SCAN_CHUNK + t * 8;
    int c[8], loc[8];
    int s = 0;
#pragma unroll
    for (int j = 0; j < 8; j++) {
        int i = base + j;
        c[j] = (i < n) ? cnt[i] : 0;
        loc[j] = s;
        s += c[j];
    }
    __shared__ int sh[256];
    sh[t] = s;
    __syncthreads();
    for (int d = 1; d < 256; d <<= 1) {
        int u = (t >= d) ? sh[t - d] : 0;
        __syncthreads();
        sh[t] += u;
        __syncthreads();
    }
    const int texcl = sh[t] - s + bsum[blockIdx.x];
#pragma unroll
    for (int j = 0; j < 8; j++) {
        int i = base + j;
        if (i < n) {
            int o = texcl + loc[j];
            off[i] = o;
            if (cursor) cursor[i] = o;
            if (dis) dis[i] = rsqrtf((float)c[j] + 1.0f);
        }
    }
}

// ---------------- bucket cursor init: bcur[b] = roff[min(b*64, N)] ----------------
__global__ void k_binit(const int* __restrict__ roff, int* __restrict__ bcur,
                        int nbuck, int N) {
    int b = blockIdx.x * blockDim.x + threadIdx.x;
    if (b < nbuck) bcur[b] = roff[min(b * BUCKN, N)];
}

// ---------------- phase 1: scatter (src,tgt) pairs into coarse buckets ----------------
__global__ void k_bscatter(const int* __restrict__ src, const int* __restrict__ tgt,
                           int* __restrict__ bcur, int2* __restrict__ pairs, int E) {
    int i = blockIdx.x * blockDim.x + threadIdx.x;
    if (i < E) {
        int t = tgt[i];
        int p = atomicAdd(&bcur[t >> BSH], 1);
        pairs[p] = make_int2(src[i], t);
    }
}

// ---------------- phase 2: per-bucket exact counting sort into esrc ----------------
__global__ __launch_bounds__(256) void k_fill2(const int2* __restrict__ pairs,
                                               const int* __restrict__ roff,
                                               int* __restrict__ cursor,
                                               int* __restrict__ esrc, int N) {
    const int b = blockIdx.x;
    const int lo = roff[min(b * BUCKN, N)];
    const int hi = roff[min((b + 1) * BUCKN, N)];
    for (int p = lo + threadIdx.x; p < hi; p += 256) {
        int2 e = pairs[p];
        int q = atomicAdd(&cursor[e.y], 1);  // cursor lines local to this block
        esrc[q] = e.x;
    }
}

// ---------------- GEMM: Ybf16[N,M] = (BN?(X)[N,128] @ W[128,M]) * dis[row] ----------------
template <int M, bool BN>
__global__ __launch_bounds__(256) void k_gemm2(const float* __restrict__ X,
                                               const float* __restrict__ W,
                                               unsigned short* __restrict__ Y, int N,
                                               const float* __restrict__ dis,
                                               const float* __restrict__ sums,
                                               const float* __restrict__ sumsq,
                                               const float* __restrict__ g,
                                               const float* __restrict__ be,
                                               float inv_n) {
    __shared__ float xt[128][64];  // [k][row]
    __shared__ float wt[128][64];  // [k][col]
    const int t = threadIdx.x;
    const int rbase = blockIdx.x * 64;
    const int cbase = blockIdx.y * 64;

    for (int it = 0; it < 8; it++) {
        int idx = t + it * 256;
        int k4 = idx >> 6;
        int r = idx & 63;
        int row = rbase + r;
        float4 v = make_float4(0.f, 0.f, 0.f, 0.f);
        if (row < N) v = *(const float4*)(X + (size_t)row * 128 + k4 * 4);
        if (BN) {
            float o[4] = {v.x, v.y, v.z, v.w};
#pragma unroll
            for (int j = 0; j < 4; j++) {
                int c = k4 * 4 + j;
                float mean = sums[c] * inv_n;
                float var = sumsq[c] * inv_n - mean * mean;
                float sc = rsqrtf(var + BN_EPS) * g[c];
                o[j] = fmaxf((o[j] - mean) * sc + be[c], 0.0f);
            }
            v.x = o[0]; v.y = o[1]; v.z = o[2]; v.w = o[3];
        }
        xt[k4 * 4 + 0][r] = v.x;
        xt[k4 * 4 + 1][r] = v.y;
        xt[k4 * 4 + 2][r] = v.z;
        xt[k4 * 4 + 3][r] = v.w;
    }
    for (int it = 0; it < 8; it++) {
        int idx = t + it * 256;
        int k = idx >> 4;
        int c4 = (idx & 15) * 4;
        *(float4*)&wt[k][c4] = *(const float4*)(W + (size_t)k * M + cbase + c4);
    }
    __syncthreads();

    const int r0 = (t >> 4) * 4;
    const int c0 = (t & 15) * 4;
    float acc[4][4];
#pragma unroll
    for (int i = 0; i < 4; i++)
#pragma unroll
        for (int j = 0; j < 4; j++) acc[i][j] = 0.0f;

#pragma unroll 4
    for (int k = 0; k < 128; k++) {
        float4 a = *(const float4*)&xt[k][r0];
        float4 b = *(const float4*)&wt[k][c0];
        const float av[4] = {a.x, a.y, a.z, a.w};
        const float bv[4] = {b.x, b.y, b.z, b.w};
#pragma unroll
        for (int i = 0; i < 4; i++)
#pragma unroll
            for (int j = 0; j < 4; j++) acc[i][j] += av[i] * bv[j];
    }

#pragma unroll
    for (int i = 0; i < 4; i++) {
        int row = rbase + r0 + i;
        if (row < N) {
            const float dv = dis[row];
            ushort4 o;
            o.x = f2bf(acc[i][0] * dv);
            o.y = f2bf(acc[i][1] * dv);
            o.z = f2bf(acc[i][2] * dv);
            o.w = f2bf(acc[i][3] * dv);
            *(ushort4*)(Y + (size_t)row * M + cbase + c0) = o;
        }
    }
}

// ---------------- final GEMM: out[G,256] = P[G,128] @ W3 + b3 (empty-graph guard) ----------------
__global__ __launch_bounds__(256) void k_gemm_final(const float* __restrict__ X,
                                                    const float* __restrict__ W,
                                                    const float* __restrict__ bias,
                                                    const int* __restrict__ goff,
                                                    float* __restrict__ out, int G) {
    __shared__ float xt[128][64];
    __shared__ float wt[128][64];
    const int t = threadIdx.x;
    const int rbase = blockIdx.x * 64;
    const int cbase = blockIdx.y * 64;

    for (int it = 0; it < 8; it++) {
        int idx = t + it * 256;
        int k4 = idx >> 6;
        int r = idx & 63;
        int row = rbase + r;
        float4 v = make_float4(0.f, 0.f, 0.f, 0.f);
        if (row < G) v = *(const float4*)(X + (size_t)row * 128 + k4 * 4);
        xt[k4 * 4 + 0][r] = v.x;
        xt[k4 * 4 + 1][r] = v.y;
        xt[k4 * 4 + 2][r] = v.z;
        xt[k4 * 4 + 3][r] = v.w;
    }
    for (int it = 0; it < 8; it++) {
        int idx = t + it * 256;
        int k = idx >> 4;
        int c4 = (idx & 15) * 4;
        *(float4*)&wt[k][c4] = *(const float4*)(W + (size_t)k * 256 + cbase + c4);
    }
    __syncthreads();

    const int r0 = (t >> 4) * 4;
    const int c0 = (t & 15) * 4;
    float acc[4][4];
#pragma unroll
    for (int i = 0; i < 4; i++)
#pragma unroll
        for (int j = 0; j < 4; j++) acc[i][j] = 0.0f;

#pragma unroll 4
    for (int k = 0; k < 128; k++) {
        float4 a = *(const float4*)&xt[k][r0];
        float4 b = *(const float4*)&wt[k][c0];
        const float av[4] = {a.x, a.y, a.z, a.w};
        const float bv[4] = {b.x, b.y, b.z, b.w};
#pragma unroll
        for (int i = 0; i < 4; i++)
#pragma unroll
            for (int j = 0; j < 4; j++) acc[i][j] += av[i] * bv[j];
    }

#pragma unroll
    for (int i = 0; i < 4; i++) {
        int row = rbase + r0 + i;
        if (row < G) {
            bool empty = (goff[row + 1] == goff[row]);
            float4 o;
            o.x = empty ? 0.f : acc[i][0] + bias[cbase + c0 + 0];
            o.y = empty ? 0.f : acc[i][1] + bias[cbase + c0 + 1];
            o.z = empty ? 0.f : acc[i][2] + bias[cbase + c0 + 2];
            o.w = empty ? 0.f : acc[i][3] + bias[cbase + c0 + 3];
            *(float4*)(out + (size_t)row * 256 + cbase + c0) = o;
        }
    }
}

// ---------------- CSR aggregation: H pre-scaled by dis; out = dn*(sum + self) + b ----------------
template <int M>
__global__ __launch_bounds__(256) void k_aggr2(const unsigned short* __restrict__ H,
                                               const int* __restrict__ esrc,
                                               const int* __restrict__ roff,
                                               const float* __restrict__ dis,
                                               const float* __restrict__ bias,
                                               float* __restrict__ out, int N) {
    constexpr int GSZ = M / 8;       // lanes per row (16 for M=128)
    constexpr int GPB = 256 / GSZ;   // groups per block
    const int nGroups = gridDim.x * GPB;
    const int gid = blockIdx.x * GPB + threadIdx.x / GSZ;
    const int lane = threadIdx.x % GSZ;
    const int c8 = lane * 8;
    const float4 bva = *(const float4*)(bias + c8);
    const float4 bvb = *(const float4*)(bias + c8 + 4);

    for (int n = gid; n < N; n += nGroups) {
        const int rs = roff[n], re = roff[n + 1];
        float acc[8];
#pragma unroll
        for (int j = 0; j < 8; j++) acc[j] = 0.0f;

        int e = rs;
        for (; e + 4 <= re; e += 4) {
            const int s0 = esrc[e + 0];
            const int s1 = esrc[e + 1];
            const int s2 = esrc[e + 2];
            const int s3 = esrc[e + 3];
            const int4 h0 = *(const int4*)(H + (size_t)s0 * M + c8);
            const int4 h1 = *(const int4*)(H + (size_t)s1 * M + c8);
            const int4 h2 = *(const int4*)(H + (size_t)s2 * M + c8);
            const int4 h3 = *(const int4*)(H + (size_t)s3 * M + c8);
            const int w0[4] = {h0.x, h0.y, h0.z, h0.w};
            const int w1[4] = {h1.x, h1.y, h1.z, h1.w};
            const int w2[4] = {h2.x, h2.y, h2.z, h2.w};
            const int w3[4] = {h3.x, h3.y, h3.z, h3.w};
#pragma unroll
            for (int k = 0; k < 4; k++) {
                acc[2 * k + 0] += lo16(w0[k]) + lo16(w1[k]) + lo16(w2[k]) + lo16(w3[k]);
                acc[2 * k + 1] += hi16(w0[k]) + hi16(w1[k]) + hi16(w2[k]) + hi16(w3[k]);
            }
        }
        for (; e < re; e++) {  // tail (<=3)
            const int s = esrc[e];
            const int4 h = *(const int4*)(H + (size_t)s * M + c8);
            const int w[4] = {h.x, h.y, h.z, h.w};
#pragma unroll
            for (int k = 0; k < 4; k++) {
                acc[2 * k + 0] += lo16(w[k]);
                acc[2 * k + 1] += hi16(w[k]);
            }
        }

        // self term (H[n] already carries one dis factor)
        {
            const int4 h = *(const int4*)(H + (size_t)n * M + c8);
            const int w[4] = {h.x, h.y, h.z, h.w};
#pragma unroll
            for (int k = 0; k < 4; k++) {
                acc[2 * k + 0] += lo16(w[k]);
                acc[2 * k + 1] += hi16(w[k]);
            }
        }
        const float dn = dis[n];
        float4 oa, ob;
        oa.x = acc[0] * dn + bva.x;
        oa.y = acc[1] * dn + bva.y;
        oa.z = acc[2] * dn + bva.z;
        oa.w = acc[3] * dn + bva.w;
        ob.x = acc[4] * dn + bvb.x;
        ob.y = acc[5] * dn + bvb.y;
        ob.z = acc[6] * dn + bvb.z;
        ob.w = acc[7] * dn + bvb.w;
        *(float4*)(out + (size_t)n * M + c8) = oa;
        *(float4*)(out + (size_t)n * M + c8 + 4) = ob;
    }
}

// ---------------- BN stats ----------------
__global__ __launch_bounds__(256) void k_bnstats(const float* __restrict__ X,
                                                 float* __restrict__ sums,
                                                 float* __restrict__ sumsq, int N) {
    __shared__ float s1[256], s2[256];
    const int t = threadIdx.x;
    const int c = t & 127, half = t >> 7;
    float a = 0.0f, b = 0.0f;
    for (long long row = (long long)blockIdx.x * 2 + half; row < N; row += (long long)gridDim.x * 2) {
        float v = X[row * 128 + c];
        a += v;
        b += v * v;
    }
    s1[t] = a;
    s2[t] = b;
    __syncthreads();
    if (half == 0) {
        a = s1[t] + s1[t + 128];
        b = s2[t] + s2[t + 128];
        atomicAdd(&sums[c], a);
        atomicAdd(&sumsq[c], b);
    }
}

// ---------------- BN+ReLU -> bf16 cast, pre-scaled by dis ----------------
__global__ void k_bncast(const float* __restrict__ X, const float* __restrict__ sums,
                         const float* __restrict__ sumsq, const float* __restrict__ g,
                         const float* __restrict__ be, const float* __restrict__ dis,
                         unsigned short* __restrict__ Y, long long total4, float inv_n) {
    long long idx = (long long)blockIdx.x * blockDim.x + threadIdx.x;
    if (idx >= total4) return;
    int c4 = ((int)idx & 31) << 2;
    const float dn = dis[(int)(idx >> 5)];
    float4 v = *(const float4*)(X + idx * 4);
    float o[4] = {v.x, v.y, v.z, v.w};
    ushort4 r;
    unsigned short* rp = &r.x;
#pragma unroll
    for (int j = 0; j < 4; j++) {
        int c = c4 + j;
        float mean = sums[c] * inv_n;
        float var = sumsq[c] * inv_n - mean * mean;
        float sc = rsqrtf(var + BN_EPS) * g[c];
        rp[j] = f2bf(fmaxf((o[j] - mean) * sc + be[c], 0.0f) * dn);
    }
    *(ushort4*)(Y + idx * 4) = r;
}

// ---------------- segmented mean pool (batch sorted) ----------------
template <int M>
__global__ void k_pool_seg(const float* __restrict__ H, const int* __restrict__ goff,
                           float* __restrict__ out) {
    const int gr = blockIdx.x;
    const int c = threadIdx.x;
    const int s = goff[gr], e = goff[gr + 1];
    float acc = 0.0f;
    for (int i = s; i < e; i++) acc += H[(size_t)i * M + c];
    out[(size_t)gr * M + c] = acc / fmaxf((float)(e - s), 1.0f);
}

extern "C" void kernel_launch(void* const* d_in, const int* in_sizes, int n_in,
                              void* d_out, int out_size, void* d_ws, size_t ws_size,
                              hipStream_t stream) {
    const float* x     = (const float*)d_in[0];
    const int*   ei    = (const int*)d_in[1];
    const int*   batch = (const int*)d_in[2];
    const float* W1 = (const float*)d_in[3];
    const float* b1 = (const float*)d_in[4];
    const float* W2 = (const float*)d_in[5];
    const float* b2 = (const float*)d_in[6];
    const float* W3 = (const float*)d_in[7];
    const float* b3 = (const float*)d_in[8];
    const float* g1 = (const float*)d_in[9];
    const float* be1 = (const float*)d_in[10];
    const float* g2 = (const float*)d_in[11];
    const float* be2 = (const float*)d_in[12];
    float* out = (float*)d_out;

    const int N = in_sizes[2];
    const int E = in_sizes[1] / 2;
    const int G = out_size / 256;
    const int* src = ei;
    const int* tgt = ei + E;

    char* ws = (char*)d_ws;
    auto take = [&](size_t bytes) {
        char* p = ws;
        ws += (bytes + 255) & ~(size_t)255;
        return p;
    };
    float*          bufB   = (float*)take((size_t)N * 128 * 4);   // f32 agg outputs (also aliased as pairs)
    unsigned short* bufH   = (unsigned short*)take((size_t)N * 128 * 2);
    float*          P      = (float*)take((size_t)G * 128 * 4);
    float*          dis    = (float*)take((size_t)N * 4);
    float*          sums   = (float*)take(512 * 4);
    float*          sumsq  = sums + 128;
    float*          zbias  = (float*)take(128 * 4);
    int*            ncnt   = (int*)take((size_t)N * 4);
    int*            roff   = (int*)take((size_t)(N + 1) * 4);
    int*            cursor = (int*)take((size_t)N * 4);
    int*            esrc   = (int*)take((size_t)E * 4);
    int*            gcnt   = (int*)take((size_t)G * 4);
    int*            goff   = (int*)take((size_t)(G + 1) * 4);
    int*            bsumN  = (int*)take(256 * 4);
    int*            bsumG  = (int*)take(256 * 4);
    const int nbuck = cdiv(N, BUCKN);
    int*            bcur   = (int*)take((size_t)nbuck * 4);
    int2*           pairs  = (int2*)bufB;  // alias: consumed by k_fill2 before bufB's first write

    const int B = 256;
    const int AGG_BLOCKS = 2048;
    const int nbN = cdiv(N, SCAN_CHUNK);
    const int nbG = cdiv(G, SCAN_CHUNK);

    // ---- CSR build ----
    hipMemsetAsync(ncnt, 0, (size_t)N * 4, stream);
    hipMemsetAsync(gcnt, 0, (size_t)G * 4, stream);
    hipMemsetAsync(zbias, 0, 128 * 4, stream);
    k_hist<<<cdiv(E, B), B, 0, stream>>>(tgt, ncnt, E);
    k_hist<<<cdiv(N, B), B, 0, stream>>>(batch, gcnt, N);
    k_scan_blk<<<nbN, B, 0, stream>>>(ncnt, bsumN, N);
    k_scan_bsum<<<1, B, 0, stream>>>(bsumN, roff, nbN, N);
    k_scan_out<<<nbN, B, 0, stream>>>(ncnt, bsumN, roff, N, dis, cursor);
    k_scan_blk<<<nbG, B, 0, stream>>>(gcnt, bsumG, G);
    k_scan_bsum<<<1, B, 0, stream>>>(bsumG, goff, nbG, G);
    k_scan_out<<<nbG, B, 0, stream>>>(gcnt, bsumG, goff, G, nullptr, nullptr);
    k_binit<<<cdiv(nbuck, B), B, 0, stream>>>(roff, bcur, nbuck, N);
    k_bscatter<<<cdiv(E, B), B, 0, stream>>>(src, tgt, bcur, pairs, E);
    k_fill2<<<nbuck, B, 0, stream>>>(pairs, roff, cursor, esrc, N);

    long long t4_128 = (long long)N * 32;

    // ---- layer 1 ----
    k_gemm2<128, false><<<dim3(cdiv(N, 64), 2), B, 0, stream>>>(x, W1, bufH, N, dis,
                                                                nullptr, nullptr, nullptr, nullptr, 0.f);
    k_aggr2<128><<<AGG_BLOCKS, B, 0, stream>>>(bufH, esrc, roff, dis, b1, bufB, N);
    hipMemsetAsync(sums, 0, 256 * 4, stream);
    k_bnstats<<<1024, B, 0, stream>>>(bufB, sums, sumsq, N);

    // ---- layer 2 (BN1 fused into GEMM staging) ----
    k_gemm2<128, true><<<dim3(cdiv(N, 64), 2), B, 0, stream>>>(bufB, W2, bufH, N, dis,
                                                               sums, sumsq, g1, be1, 1.0f / N);
    k_aggr2<128><<<AGG_BLOCKS, B, 0, stream>>>(bufH, esrc, roff, dis, b2, bufB, N);
    hipMemsetAsync(sums, 0, 256 * 4, stream);
    k_bnstats<<<1024, B, 0, stream>>>(bufB, sums, sumsq, N);

    // ---- layer 3: BN2+ReLU+dis cast -> aggregate 128-dim -> pool -> small GEMM ----
    k_bncast<<<cdiv(t4_128, B), B, 0, stream>>>(bufB, sums, sumsq, g2, be2, dis, bufH,
                                                t4_128, 1.0f / N);
    k_aggr2<128><<<AGG_BLOCKS, B, 0, stream>>>(bufH, esrc, roff, dis, zbias, bufB, N);
    k_pool_seg<128><<<G, 128, 0, stream>>>(bufB, goff, P);
    k_gemm_final<<<dim3(cdiv(G, 64), 4), B, 0, stream>>>(P, W3, b3, goff, out, G);
}

// Round 7
// 548.094 us; speedup vs baseline: 1.5222x; 1.5222x over previous
//
#include <hip/hip_runtime.h>
#include <hip/hip_bf16.h>

#define BN_EPS 1e-5f
#define SCAN_CHUNK 2048  // 256 threads * 8 elems
#define AGG_BLOCKS 2048

static inline int cdiv(long long a, long long b) { return (int)((a + b - 1) / b); }

typedef __attribute__((ext_vector_type(8))) short short8v;
typedef __attribute__((ext_vector_type(4))) float f32x4;

__device__ __forceinline__ float lo16(int u) {
    return __uint_as_float(((unsigned int)u) << 16);
}
__device__ __forceinline__ float hi16(int u) {
    return __uint_as_float(((unsigned int)u) & 0xffff0000u);
}
__device__ __forceinline__ unsigned short f2bf(float f) {
    unsigned int b = __float_as_uint(f);
    b += 0x7FFFu + ((b >> 16) & 1u);  // RNE
    return (unsigned short)(b >> 16);
}

// ---------------- histogram ----------------
__global__ void k_hist(const int* __restrict__ idx, int* __restrict__ cnt, int n) {
    int i = blockIdx.x * blockDim.x + threadIdx.x;
    if (i < n) atomicAdd(&cnt[idx[i]], 1);
}

// ---------------- hierarchical scan: pass 1 (block sums) ----------------
__global__ __launch_bounds__(256) void k_scan_blk(const int* __restrict__ cnt,
                                                  int* __restrict__ bsum, int n) {
    const int t = threadIdx.x;
    const int base = blockIdx.x * SCAN_CHUNK + t * 8;
    int s = 0;
    if (base + 8 <= n) {
        int4 a = *(const int4*)(cnt + base);
        int4 b = *(const int4*)(cnt + base + 4);
        s = a.x + a.y + a.z + a.w + b.x + b.y + b.z + b.w;
    } else {
#pragma unroll
        for (int j = 0; j < 8; j++) {
            int i = base + j;
            if (i < n) s += cnt[i];
        }
    }
    __shared__ int red[256];
    red[t] = s;
    __syncthreads();
    for (int d = 128; d > 0; d >>= 1) {
        if (t < d) red[t] += red[t + d];
        __syncthreads();
    }
    if (t == 0) bsum[blockIdx.x] = red[0];
}

// ---------------- pass 2: scan of block sums (nb <= 256) ----------------
__global__ __launch_bounds__(256) void k_scan_bsum(int* __restrict__ bsum,
                                                   int* __restrict__ off, int nb, int n) {
    const int t = threadIdx.x;
    __shared__ int sh[256];
    int v = (t < nb) ? bsum[t] : 0;
    sh[t] = v;
    __syncthreads();
    for (int d = 1; d < 256; d <<= 1) {
        int u = (t >= d) ? sh[t - d] : 0;
        __syncthreads();
        sh[t] += u;
        __syncthreads();
    }
    if (t < nb) bsum[t] = sh[t] - v;  // exclusive block offset
    if (t == 255) off[n] = sh[255];   // grand total
}

// ---------------- pass 3: write exclusive offsets (+ optional dis/cursor) ----------------
__global__ __launch_bounds__(256) void k_scan_out(const int* __restrict__ cnt,
                                                  const int* __restrict__ bsum,
                                                  int* __restrict__ off, int n,
                                                  float* __restrict__ dis,
                                                  int* __restrict__ cursor) {
    const int t = threadIdx.x;
    const int base = blockIdx.x * SCAN_CHUNK + t * 8;
    int c[8], loc[8];
    int s = 0;
#pragma unroll
    for (int j = 0; j < 8; j++) {
        int i = base + j;
        c[j] = (i < n) ? cnt[i] : 0;
        loc[j] = s;
        s += c[j];
    }
    __shared__ int sh[256];
    sh[t] = s;
    __syncthreads();
    for (int d = 1; d < 256; d <<= 1) {
        int u = (t >= d) ? sh[t - d] : 0;
        __syncthreads();
        sh[t] += u;
        __syncthreads();
    }
    const int texcl = sh[t] - s + bsum[blockIdx.x];
#pragma unroll
    for (int j = 0; j < 8; j++) {
        int i = base + j;
        if (i < n) {
            int o = texcl + loc[j];
            off[i] = o;
            if (cursor) cursor[i] = o;
            if (dis) dis[i] = rsqrtf((float)c[j] + 1.0f);
        }
    }
}

// ---------------- CSR fill (single-phase, uncontended per-node cursors) ----------------
__global__ void k_fill(const int* __restrict__ src, const int* __restrict__ tgt,
                       int* __restrict__ cursor, int* __restrict__ esrc, int E) {
    int i = blockIdx.x * blockDim.x + threadIdx.x;
    if (i < E) {
        int t = tgt[i];
        int p = atomicAdd(&cursor[t], 1);
        esrc[p] = src[i];
    }
}

// ---------------- MFMA GEMM: Ybf16[N,128] = (BN?(X) @ W[128,128]) * dis[row] ----------------
template <bool BN>
__global__ __launch_bounds__(256) void k_gemm_mfma(const float* __restrict__ X,
                                                   const float* __restrict__ W,
                                                   unsigned short* __restrict__ Y, int N,
                                                   const float* __restrict__ dis,
                                                   const float* __restrict__ sums,
                                                   const float* __restrict__ sumsq,
                                                   const float* __restrict__ g,
                                                   const float* __restrict__ be,
                                                   float inv_n) {
    __shared__ unsigned short As[64][136];  // [row][k] bf16, pad for bank spread
    __shared__ unsigned short Bs[64][136];  // [col][k] bf16 (W transposed)
    const int t = threadIdx.x;
    const int rbase = blockIdx.x * 64;
    const int cbase = blockIdx.y * 64;

    // stage A: 64 rows x 128 k, f32 -> (BN+ReLU) -> bf16
    for (int it = 0; it < 8; it++) {
        int idx = t + it * 256;   // 2048 float4 groups
        int r = idx >> 5;
        int k4 = (idx & 31) * 4;
        int row = rbase + r;
        float4 v = make_float4(0.f, 0.f, 0.f, 0.f);
        if (row < N) v = *(const float4*)(X + (size_t)row * 128 + k4);
        float o[4] = {v.x, v.y, v.z, v.w};
        if (BN) {
#pragma unroll
            for (int j = 0; j < 4; j++) {
                int c = k4 + j;
                float mean = sums[c] * inv_n;
                float var = sumsq[c] * inv_n - mean * mean;
                float sc = rsqrtf(var + BN_EPS) * g[c];
                o[j] = fmaxf((o[j] - mean) * sc + be[c], 0.0f);
            }
        }
        ushort4 u;
        u.x = f2bf(o[0]); u.y = f2bf(o[1]); u.z = f2bf(o[2]); u.w = f2bf(o[3]);
        *(ushort4*)&As[r][k4] = u;
    }
    // stage B: W[k][cbase+c] -> Bs[c][k]
    for (int it = 0; it < 8; it++) {
        int idx = t + it * 256;
        int k = idx >> 4;
        int c4 = (idx & 15) * 4;
        float4 v = *(const float4*)(W + (size_t)k * 128 + cbase + c4);
        Bs[c4 + 0][k] = f2bf(v.x);
        Bs[c4 + 1][k] = f2bf(v.y);
        Bs[c4 + 2][k] = f2bf(v.z);
        Bs[c4 + 3][k] = f2bf(v.w);
    }
    __syncthreads();

    const int wid = t >> 6;
    const int lane = t & 63;
    const int wr = (wid >> 1) * 32;
    const int wc = (wid & 1) * 32;
    const int lrow = lane & 15;
    const int lkg = lane >> 4;

    f32x4 acc00 = 0, acc01 = 0, acc10 = 0, acc11 = 0;
#pragma unroll
    for (int kk = 0; kk < 4; kk++) {
        const int k0 = kk * 32 + lkg * 8;
        short8v a0 = *(const short8v*)&As[wr + lrow][k0];
        short8v a1 = *(const short8v*)&As[wr + 16 + lrow][k0];
        short8v b0 = *(const short8v*)&Bs[wc + lrow][k0];
        short8v b1 = *(const short8v*)&Bs[wc + 16 + lrow][k0];
        acc00 = __builtin_amdgcn_mfma_f32_16x16x32_bf16(a0, b0, acc00, 0, 0, 0);
        acc01 = __builtin_amdgcn_mfma_f32_16x16x32_bf16(a0, b1, acc01, 0, 0, 0);
        acc10 = __builtin_amdgcn_mfma_f32_16x16x32_bf16(a1, b0, acc10, 0, 0, 0);
        acc11 = __builtin_amdgcn_mfma_f32_16x16x32_bf16(a1, b1, acc11, 0, 0, 0);
    }

#pragma unroll
    for (int rt = 0; rt < 2; rt++) {
        const f32x4 va = rt ? acc10 : acc00;
        const f32x4 vb = rt ? acc11 : acc01;
#pragma unroll
        for (int reg = 0; reg < 4; reg++) {
            int row = rbase + wr + rt * 16 + lkg * 4 + reg;
            if (row < N) {
                float dv = dis[row];
                Y[(size_t)row * 128 + cbase + wc + lrow] = f2bf(va[reg] * dv);
                Y[(size_t)row * 128 + cbase + wc + 16 + lrow] = f2bf(vb[reg] * dv);
            }
        }
    }
}

// ---------------- final GEMM: out[G,256] = P[G,128] @ W3 + b3 (empty-graph guard) ----------------
__global__ __launch_bounds__(256) void k_gemm_final(const float* __restrict__ X,
                                                    const float* __restrict__ W,
                                                    const float* __restrict__ bias,
                                                    const int* __restrict__ goff,
                                                    float* __restrict__ out, int G) {
    __shared__ float xt[128][64];
    __shared__ float wt[128][64];
    const int t = threadIdx.x;
    const int rbase = blockIdx.x * 64;
    const int cbase = blockIdx.y * 64;

    for (int it = 0; it < 8; it++) {
        int idx = t + it * 256;
        int k4 = idx >> 6;
        int r = idx & 63;
        int row = rbase + r;
        float4 v = make_float4(0.f, 0.f, 0.f, 0.f);
        if (row < G) v = *(const float4*)(X + (size_t)row * 128 + k4 * 4);
        xt[k4 * 4 + 0][r] = v.x;
        xt[k4 * 4 + 1][r] = v.y;
        xt[k4 * 4 + 2][r] = v.z;
        xt[k4 * 4 + 3][r] = v.w;
    }
    for (int it = 0; it < 8; it++) {
        int idx = t + it * 256;
        int k = idx >> 4;
        int c4 = (idx & 15) * 4;
        *(float4*)&wt[k][c4] = *(const float4*)(W + (size_t)k * 256 + cbase + c4);
    }
    __syncthreads();

    const int r0 = (t >> 4) * 4;
    const int c0 = (t & 15) * 4;
    float acc[4][4];
#pragma unroll
    for (int i = 0; i < 4; i++)
#pragma unroll
        for (int j = 0; j < 4; j++) acc[i][j] = 0.0f;

#pragma unroll 4
    for (int k = 0; k < 128; k++) {
        float4 a = *(const float4*)&xt[k][r0];
        float4 b = *(const float4*)&wt[k][c0];
        const float av[4] = {a.x, a.y, a.z, a.w};
        const float bv[4] = {b.x, b.y, b.z, b.w};
#pragma unroll
        for (int i = 0; i < 4; i++)
#pragma unroll
            for (int j = 0; j < 4; j++) acc[i][j] += av[i] * bv[j];
    }

#pragma unroll
    for (int i = 0; i < 4; i++) {
        int row = rbase + r0 + i;
        if (row < G) {
            bool empty = (goff[row + 1] == goff[row]);
            float4 o;
            o.x = empty ? 0.f : acc[i][0] + bias[cbase + c0 + 0];
            o.y = empty ? 0.f : acc[i][1] + bias[cbase + c0 + 1];
            o.z = empty ? 0.f : acc[i][2] + bias[cbase + c0 + 2];
            o.w = empty ? 0.f : acc[i][3] + bias[cbase + c0 + 3];
            *(float4*)(out + (size_t)row * 256 + cbase + c0) = o;
        }
    }
}

// ---------------- CSR aggregation (H pre-scaled by dis) + optional fused BN stats ----------------
// out[n] = dn*(sum_edges H[s] + H[n]) + b ; STATS: per-block partial sum/sumsq of out
template <bool STATS>
__global__ __launch_bounds__(256) void k_aggr2(const unsigned short* __restrict__ H,
                                               const int* __restrict__ esrc,
                                               const int* __restrict__ roff,
                                               const float* __restrict__ dis,
                                               const float* __restrict__ bias,
                                               float* __restrict__ out, int N,
                                               float* __restrict__ partial) {
    constexpr int M = 128;
    constexpr int GSZ = 16;   // lanes per row (int4 = 8 bf16 each)
    constexpr int GPB = 16;   // groups per block
    const int nGroups = gridDim.x * GPB;
    const int gid = blockIdx.x * GPB + threadIdx.x / GSZ;
    const int lane = threadIdx.x % GSZ;
    const int c8 = lane * 8;
    const float4 bva = *(const float4*)(bias + c8);
    const float4 bvb = *(const float4*)(bias + c8 + 4);

    float ss[8], sq[8];
    if (STATS) {
#pragma unroll
        for (int k = 0; k < 8; k++) { ss[k] = 0.f; sq[k] = 0.f; }
    }

    for (int n = gid; n < N; n += nGroups) {
        const int rs = roff[n], re = roff[n + 1];
        float acc[8];
#pragma unroll
        for (int j = 0; j < 8; j++) acc[j] = 0.0f;

        int e = rs;
        for (; e + 4 <= re; e += 4) {
            const int s0 = esrc[e + 0];
            const int s1 = esrc[e + 1];
            const int s2 = esrc[e + 2];
            const int s3 = esrc[e + 3];
            const int4 h0 = *(const int4*)(H + (size_t)s0 * M + c8);
            const int4 h1 = *(const int4*)(H + (size_t)s1 * M + c8);
            const int4 h2 = *(const int4*)(H + (size_t)s2 * M + c8);
            const int4 h3 = *(const int4*)(H + (size_t)s3 * M + c8);
            const int w0[4] = {h0.x, h0.y, h0.z, h0.w};
            const int w1[4] = {h1.x, h1.y, h1.z, h1.w};
            const int w2[4] = {h2.x, h2.y, h2.z, h2.w};
            const int w3[4] = {h3.x, h3.y, h3.z, h3.w};
#pragma unroll
            for (int k = 0; k < 4; k++) {
                acc[2 * k + 0] += lo16(w0[k]) + lo16(w1[k]) + lo16(w2[k]) + lo16(w3[k]);
                acc[2 * k + 1] += hi16(w0[k]) + hi16(w1[k]) + hi16(w2[k]) + hi16(w3[k]);
            }
        }
        for (; e < re; e++) {
            const int s = esrc[e];
            const int4 h = *(const int4*)(H + (size_t)s * M + c8);
            const int w[4] = {h.x, h.y, h.z, h.w};
#pragma unroll
            for (int k = 0; k < 4; k++) {
                acc[2 * k + 0] += lo16(w[k]);
                acc[2 * k + 1] += hi16(w[k]);
            }
        }
        {
            const int4 h = *(const int4*)(H + (size_t)n * M + c8);
            const int w[4] = {h.x, h.y, h.z, h.w};
#pragma unroll
            for (int k = 0; k < 4; k++) {
                acc[2 * k + 0] += lo16(w[k]);
                acc[2 * k + 1] += hi16(w[k]);
            }
        }
        const float dn = dis[n];
        float ov[8];
#pragma unroll
        for (int k = 0; k < 8; k++) {
            float b = (k < 4) ? (&bva.x)[k] : (&bvb.x)[k - 4];
            ov[k] = acc[k] * dn + b;
            if (STATS) { ss[k] += ov[k]; sq[k] += ov[k] * ov[k]; }
        }
        float4 oa = make_float4(ov[0], ov[1], ov[2], ov[3]);
        float4 ob = make_float4(ov[4], ov[5], ov[6], ov[7]);
        *(float4*)(out + (size_t)n * M + c8) = oa;
        *(float4*)(out + (size_t)n * M + c8 + 4) = ob;
    }

    if (STATS) {
        __shared__ float ls[GPB][256];
        const int g = threadIdx.x / GSZ;
#pragma unroll
        for (int k = 0; k < 8; k++) {
            ls[g][c8 + k] = ss[k];
            ls[g][128 + c8 + k] = sq[k];
        }
        __syncthreads();
        const int f = threadIdx.x;  // 0..255
        float v = 0.f;
#pragma unroll
        for (int gg = 0; gg < GPB; gg++) v += ls[gg][f];
        partial[(size_t)blockIdx.x * 256 + f] = v;
    }
}

// ---------------- reduce partial stats: grid=256 (one block per feature-slot) ----------------
__global__ __launch_bounds__(256) void k_redstats(const float* __restrict__ partial,
                                                  float* __restrict__ sums,
                                                  float* __restrict__ sumsq, int nblk) {
    const int f = blockIdx.x;  // 0..255
    const int t = threadIdx.x;
    float v = 0.f;
    for (int b = t; b < nblk; b += 256) v += partial[(size_t)b * 256 + f];
    __shared__ float sh[256];
    sh[t] = v;
    __syncthreads();
    for (int d = 128; d > 0; d >>= 1) {
        if (t < d) sh[t] += sh[t + d];
        __syncthreads();
    }
    if (t == 0) {
        if (f < 128) sums[f] = sh[0];
        else sumsq[f - 128] = sh[0];
    }
}

// ---------------- BN+ReLU -> bf16 cast, pre-scaled by dis ----------------
__global__ void k_bncast(const float* __restrict__ X, const float* __restrict__ sums,
                         const float* __restrict__ sumsq, const float* __restrict__ g,
                         const float* __restrict__ be, const float* __restrict__ dis,
                         unsigned short* __restrict__ Y, long long total4, float inv_n) {
    long long idx = (long long)blockIdx.x * blockDim.x + threadIdx.x;
    if (idx >= total4) return;
    int c4 = ((int)idx & 31) << 2;
    const float dn = dis[(int)(idx >> 5)];
    float4 v = *(const float4*)(X + idx * 4);
    float o[4] = {v.x, v.y, v.z, v.w};
    ushort4 r;
    unsigned short* rp = &r.x;
#pragma unroll
    for (int j = 0; j < 4; j++) {
        int c = c4 + j;
        float mean = sums[c] * inv_n;
        float var = sumsq[c] * inv_n - mean * mean;
        float sc = rsqrtf(var + BN_EPS) * g[c];
        rp[j] = f2bf(fmaxf((o[j] - mean) * sc + be[c], 0.0f) * dn);
    }
    *(ushort4*)(Y + idx * 4) = r;
}

// ---------------- segmented mean pool (batch sorted) ----------------
__global__ void k_pool_seg(const float* __restrict__ H, const int* __restrict__ goff,
                           float* __restrict__ out) {
    const int gr = blockIdx.x;
    const int c = threadIdx.x;  // 128
    const int s = goff[gr], e = goff[gr + 1];
    float acc = 0.0f;
    for (int i = s; i < e; i++) acc += H[(size_t)i * 128 + c];
    out[(size_t)gr * 128 + c] = acc / fmaxf((float)(e - s), 1.0f);
}

extern "C" void kernel_launch(void* const* d_in, const int* in_sizes, int n_in,
                              void* d_out, int out_size, void* d_ws, size_t ws_size,
                              hipStream_t stream) {
    const float* x     = (const float*)d_in[0];
    const int*   ei    = (const int*)d_in[1];
    const int*   batch = (const int*)d_in[2];
    const float* W1 = (const float*)d_in[3];
    const float* b1 = (const float*)d_in[4];
    const float* W2 = (const float*)d_in[5];
    const float* b2 = (const float*)d_in[6];
    const float* W3 = (const float*)d_in[7];
    const float* b3 = (const float*)d_in[8];
    const float* g1 = (const float*)d_in[9];
    const float* be1 = (const float*)d_in[10];
    const float* g2 = (const float*)d_in[11];
    const float* be2 = (const float*)d_in[12];
    float* out = (float*)d_out;

    const int N = in_sizes[2];
    const int E = in_sizes[1] / 2;
    const int G = out_size / 256;
    const int* src = ei;
    const int* tgt = ei + E;

    char* ws = (char*)d_ws;
    auto take = [&](size_t bytes) {
        char* p = ws;
        ws += (bytes + 255) & ~(size_t)255;
        return p;
    };
    float*          bufB   = (float*)take((size_t)N * 128 * 4);
    unsigned short* bufH   = (unsigned short*)take((size_t)N * 128 * 2);
    float*          P      = (float*)take((size_t)G * 128 * 4);
    float*          dis    = (float*)take((size_t)N * 4);
    float*          sums   = (float*)take(512 * 4);
    float*          sumsq  = sums + 128;
    float*          zbias  = (float*)take(128 * 4);
    float*          partial= (float*)take((size_t)AGG_BLOCKS * 256 * 4);
    int*            ncnt   = (int*)take((size_t)N * 4);
    int*            roff   = (int*)take((size_t)(N + 1) * 4);
    int*            cursor = (int*)take((size_t)N * 4);
    int*            esrc   = (int*)take((size_t)E * 4);
    int*            gcnt   = (int*)take((size_t)G * 4);
    int*            goff   = (int*)take((size_t)(G + 1) * 4);
    int*            bsumN  = (int*)take(256 * 4);
    int*            bsumG  = (int*)take(256 * 4);

    const int B = 256;
    const int nbN = cdiv(N, SCAN_CHUNK);
    const int nbG = cdiv(G, SCAN_CHUNK);

    // ---- CSR build ----
    hipMemsetAsync(ncnt, 0, (size_t)N * 4, stream);
    hipMemsetAsync(gcnt, 0, (size_t)G * 4, stream);
    hipMemsetAsync(zbias, 0, 128 * 4, stream);
    k_hist<<<cdiv(E, B), B, 0, stream>>>(tgt, ncnt, E);
    k_hist<<<cdiv(N, B), B, 0, stream>>>(batch, gcnt, N);
    k_scan_blk<<<nbN, B, 0, stream>>>(ncnt, bsumN, N);
    k_scan_bsum<<<1, B, 0, stream>>>(bsumN, roff, nbN, N);
    k_scan_out<<<nbN, B, 0, stream>>>(ncnt, bsumN, roff, N, dis, cursor);
    k_scan_blk<<<nbG, B, 0, stream>>>(gcnt, bsumG, G);
    k_scan_bsum<<<1, B, 0, stream>>>(bsumG, goff, nbG, G);
    k_scan_out<<<nbG, B, 0, stream>>>(gcnt, bsumG, goff, G, nullptr, nullptr);
    k_fill<<<cdiv(E, B), B, 0, stream>>>(src, tgt, cursor, esrc, E);

    long long t4_128 = (long long)N * 32;

    // ---- layer 1 ----
    k_gemm_mfma<false><<<dim3(cdiv(N, 64), 2), B, 0, stream>>>(x, W1, bufH, N, dis,
                                                               nullptr, nullptr, nullptr, nullptr, 0.f);
    k_aggr2<true><<<AGG_BLOCKS, B, 0, stream>>>(bufH, esrc, roff, dis, b1, bufB, N, partial);
    k_redstats<<<256, B, 0, stream>>>(partial, sums, sumsq, AGG_BLOCKS);

    // ---- layer 2 (BN1 fused into MFMA staging) ----
    k_gemm_mfma<true><<<dim3(cdiv(N, 64), 2), B, 0, stream>>>(bufB, W2, bufH, N, dis,
                                                              sums, sumsq, g1, be1, 1.0f / N);
    k_aggr2<true><<<AGG_BLOCKS, B, 0, stream>>>(bufH, esrc, roff, dis, b2, bufB, N, partial);
    k_redstats<<<256, B, 0, stream>>>(partial, sums, sumsq, AGG_BLOCKS);

    // ---- layer 3: BN2+ReLU+dis cast -> aggregate 128-dim -> pool -> small GEMM ----
    k_bncast<<<cdiv(t4_128, B), B, 0, stream>>>(bufB, sums, sumsq, g2, be2, dis, bufH,
                                                t4_128, 1.0f / N);
    k_aggr2<false><<<AGG_BLOCKS, B, 0, stream>>>(bufH, esrc, roff, dis, zbias, bufB, N, nullptr);
    k_pool_seg<<<G, 128, 0, stream>>>(bufB, goff, P);
    k_gemm_final<<<dim3(cdiv(G, 64), 4), B, 0, stream>>>(P, W3, b3, goff, out, G);
}

// Round 8
// 533.597 us; speedup vs baseline: 1.5636x; 1.0272x over previous
//
#include <hip/hip_runtime.h>
#include <hip/hip_bf16.h>

#define BN_EPS 1e-5f
#define SCAN_CHUNK 2048  // 256 threads * 8 elems
#define AGG_BLOCKS 2048

static inline int cdiv(long long a, long long b) { return (int)((a + b - 1) / b); }

typedef __attribute__((ext_vector_type(8))) short short8v;
typedef __attribute__((ext_vector_type(4))) float f32x4;

__device__ __forceinline__ float lo16(int u) {
    return __uint_as_float(((unsigned int)u) << 16);
}
__device__ __forceinline__ float hi16(int u) {
    return __uint_as_float(((unsigned int)u) & 0xffff0000u);
}
__device__ __forceinline__ unsigned short f2bf(float f) {
    unsigned int b = __float_as_uint(f);
    b += 0x7FFFu + ((b >> 16) & 1u);  // RNE
    return (unsigned short)(b >> 16);
}

// ---------------- fused histograms: edge-targets + batch ids ----------------
__global__ void k_hist2(const int* __restrict__ tgt, int* __restrict__ ncnt, int E,
                        const int* __restrict__ batch, int* __restrict__ gcnt, int N) {
    int i = blockIdx.x * blockDim.x + threadIdx.x;
    if (i < E) atomicAdd(&ncnt[tgt[i]], 1);
    if (i < N) atomicAdd(&gcnt[batch[i]], 1);
}

// ---------------- hierarchical scan: pass 1 (block sums) ----------------
__global__ __launch_bounds__(256) void k_scan_blk(const int* __restrict__ cnt,
                                                  int* __restrict__ bsum, int n) {
    const int t = threadIdx.x;
    const int base = blockIdx.x * SCAN_CHUNK + t * 8;
    int s = 0;
    if (base + 8 <= n) {
        int4 a = *(const int4*)(cnt + base);
        int4 b = *(const int4*)(cnt + base + 4);
        s = a.x + a.y + a.z + a.w + b.x + b.y + b.z + b.w;
    } else {
#pragma unroll
        for (int j = 0; j < 8; j++) {
            int i = base + j;
            if (i < n) s += cnt[i];
        }
    }
    __shared__ int red[256];
    red[t] = s;
    __syncthreads();
    for (int d = 128; d > 0; d >>= 1) {
        if (t < d) red[t] += red[t + d];
        __syncthreads();
    }
    if (t == 0) bsum[blockIdx.x] = red[0];
}

// ---------------- pass 2: scan of block sums (nb <= 256) ----------------
__global__ __launch_bounds__(256) void k_scan_bsum(int* __restrict__ bsum,
                                                   int* __restrict__ off, int nb, int n) {
    const int t = threadIdx.x;
    __shared__ int sh[256];
    int v = (t < nb) ? bsum[t] : 0;
    sh[t] = v;
    __syncthreads();
    for (int d = 1; d < 256; d <<= 1) {
        int u = (t >= d) ? sh[t - d] : 0;
        __syncthreads();
        sh[t] += u;
        __syncthreads();
    }
    if (t < nb) bsum[t] = sh[t] - v;  // exclusive block offset
    if (t == 255) off[n] = sh[255];   // grand total
}

// ---------------- pass 3: write exclusive offsets (+ optional dis/cursor) ----------------
__global__ __launch_bounds__(256) void k_scan_out(const int* __restrict__ cnt,
                                                  const int* __restrict__ bsum,
                                                  int* __restrict__ off, int n,
                                                  float* __restrict__ dis,
                                                  int* __restrict__ cursor) {
    const int t = threadIdx.x;
    const int base = blockIdx.x * SCAN_CHUNK + t * 8;
    int c[8], loc[8];
    int s = 0;
#pragma unroll
    for (int j = 0; j < 8; j++) {
        int i = base + j;
        c[j] = (i < n) ? cnt[i] : 0;
        loc[j] = s;
        s += c[j];
    }
    __shared__ int sh[256];
    sh[t] = s;
    __syncthreads();
    for (int d = 1; d < 256; d <<= 1) {
        int u = (t >= d) ? sh[t - d] : 0;
        __syncthreads();
        sh[t] += u;
        __syncthreads();
    }
    const int texcl = sh[t] - s + bsum[blockIdx.x];
#pragma unroll
    for (int j = 0; j < 8; j++) {
        int i = base + j;
        if (i < n) {
            int o = texcl + loc[j];
            off[i] = o;
            if (cursor) cursor[i] = o;
            if (dis) dis[i] = rsqrtf((float)c[j] + 1.0f);
        }
    }
}

// ---------------- fused: layer-1 MFMA GEMM tiles + CSR fill (independent work) ----------------
// blocks [0, GB): GEMM  Ybf16 = (X @ W1) * dis[row]  ;  blocks [GB, GB+FB): CSR fill
__global__ __launch_bounds__(256) void k_fill_gemm(const float* __restrict__ X,
                                                   const float* __restrict__ W,
                                                   unsigned short* __restrict__ Y, int N,
                                                   const float* __restrict__ dis,
                                                   int GB, int nbx,
                                                   const int* __restrict__ src,
                                                   const int* __restrict__ tgt,
                                                   int* __restrict__ cursor,
                                                   int* __restrict__ esrc, int E) {
    __shared__ unsigned short As[64][136];
    __shared__ unsigned short Bs[64][136];
    const int t = threadIdx.x;

    if ((int)blockIdx.x >= GB) {
        // ---- CSR fill path ----
        int i = (blockIdx.x - GB) * 256 + t;
        if (i < E) {
            int tg = tgt[i];
            int p = atomicAdd(&cursor[tg], 1);
            esrc[p] = src[i];
        }
        return;
    }

    // ---- GEMM path ----
    const int rbase = ((int)blockIdx.x % nbx) * 64;
    const int cbase = ((int)blockIdx.x / nbx) * 64;

    for (int it = 0; it < 8; it++) {
        int idx = t + it * 256;
        int r = idx >> 5;
        int k4 = (idx & 31) * 4;
        int row = rbase + r;
        float4 v = make_float4(0.f, 0.f, 0.f, 0.f);
        if (row < N) v = *(const float4*)(X + (size_t)row * 128 + k4);
        ushort4 u;
        u.x = f2bf(v.x); u.y = f2bf(v.y); u.z = f2bf(v.z); u.w = f2bf(v.w);
        *(ushort4*)&As[r][k4] = u;
    }
    for (int it = 0; it < 8; it++) {
        int idx = t + it * 256;
        int k = idx >> 4;
        int c4 = (idx & 15) * 4;
        float4 v = *(const float4*)(W + (size_t)k * 128 + cbase + c4);
        Bs[c4 + 0][k] = f2bf(v.x);
        Bs[c4 + 1][k] = f2bf(v.y);
        Bs[c4 + 2][k] = f2bf(v.z);
        Bs[c4 + 3][k] = f2bf(v.w);
    }
    __syncthreads();

    const int wid = t >> 6;
    const int lane = t & 63;
    const int wr = (wid >> 1) * 32;
    const int wc = (wid & 1) * 32;
    const int lrow = lane & 15;
    const int lkg = lane >> 4;

    f32x4 acc00 = 0, acc01 = 0, acc10 = 0, acc11 = 0;
#pragma unroll
    for (int kk = 0; kk < 4; kk++) {
        const int k0 = kk * 32 + lkg * 8;
        short8v a0 = *(const short8v*)&As[wr + lrow][k0];
        short8v a1 = *(const short8v*)&As[wr + 16 + lrow][k0];
        short8v b0 = *(const short8v*)&Bs[wc + lrow][k0];
        short8v b1 = *(const short8v*)&Bs[wc + 16 + lrow][k0];
        acc00 = __builtin_amdgcn_mfma_f32_16x16x32_bf16(a0, b0, acc00, 0, 0, 0);
        acc01 = __builtin_amdgcn_mfma_f32_16x16x32_bf16(a0, b1, acc01, 0, 0, 0);
        acc10 = __builtin_amdgcn_mfma_f32_16x16x32_bf16(a1, b0, acc10, 0, 0, 0);
        acc11 = __builtin_amdgcn_mfma_f32_16x16x32_bf16(a1, b1, acc11, 0, 0, 0);
    }

#pragma unroll
    for (int rt = 0; rt < 2; rt++) {
        const f32x4 va = rt ? acc10 : acc00;
        const f32x4 vb = rt ? acc11 : acc01;
#pragma unroll
        for (int reg = 0; reg < 4; reg++) {
            int row = rbase + wr + rt * 16 + lkg * 4 + reg;
            if (row < N) {
                float dv = dis[row];
                Y[(size_t)row * 128 + cbase + wc + lrow] = f2bf(va[reg] * dv);
                Y[(size_t)row * 128 + cbase + wc + 16 + lrow] = f2bf(vb[reg] * dv);
            }
        }
    }
}

// ---------------- MFMA GEMM: Ybf16[N,128] = (BN(X) @ W[128,128]) * dis[row] ----------------
__global__ __launch_bounds__(256) void k_gemm_mfma_bn(const float* __restrict__ X,
                                                      const float* __restrict__ W,
                                                      unsigned short* __restrict__ Y, int N,
                                                      const float* __restrict__ dis,
                                                      const float* __restrict__ sums,
                                                      const float* __restrict__ sumsq,
                                                      const float* __restrict__ g,
                                                      const float* __restrict__ be,
                                                      float inv_n) {
    __shared__ unsigned short As[64][136];
    __shared__ unsigned short Bs[64][136];
    const int t = threadIdx.x;
    const int rbase = blockIdx.x * 64;
    const int cbase = blockIdx.y * 64;

    for (int it = 0; it < 8; it++) {
        int idx = t + it * 256;
        int r = idx >> 5;
        int k4 = (idx & 31) * 4;
        int row = rbase + r;
        float4 v = make_float4(0.f, 0.f, 0.f, 0.f);
        if (row < N) v = *(const float4*)(X + (size_t)row * 128 + k4);
        float o[4] = {v.x, v.y, v.z, v.w};
#pragma unroll
        for (int j = 0; j < 4; j++) {
            int c = k4 + j;
            float mean = sums[c] * inv_n;
            float var = sumsq[c] * inv_n - mean * mean;
            float sc = rsqrtf(var + BN_EPS) * g[c];
            o[j] = fmaxf((o[j] - mean) * sc + be[c], 0.0f);
        }
        ushort4 u;
        u.x = f2bf(o[0]); u.y = f2bf(o[1]); u.z = f2bf(o[2]); u.w = f2bf(o[3]);
        *(ushort4*)&As[r][k4] = u;
    }
    for (int it = 0; it < 8; it++) {
        int idx = t + it * 256;
        int k = idx >> 4;
        int c4 = (idx & 15) * 4;
        float4 v = *(const float4*)(W + (size_t)k * 128 + cbase + c4);
        Bs[c4 + 0][k] = f2bf(v.x);
        Bs[c4 + 1][k] = f2bf(v.y);
        Bs[c4 + 2][k] = f2bf(v.z);
        Bs[c4 + 3][k] = f2bf(v.w);
    }
    __syncthreads();

    const int wid = t >> 6;
    const int lane = t & 63;
    const int wr = (wid >> 1) * 32;
    const int wc = (wid & 1) * 32;
    const int lrow = lane & 15;
    const int lkg = lane >> 4;

    f32x4 acc00 = 0, acc01 = 0, acc10 = 0, acc11 = 0;
#pragma unroll
    for (int kk = 0; kk < 4; kk++) {
        const int k0 = kk * 32 + lkg * 8;
        short8v a0 = *(const short8v*)&As[wr + lrow][k0];
        short8v a1 = *(const short8v*)&As[wr + 16 + lrow][k0];
        short8v b0 = *(const short8v*)&Bs[wc + lrow][k0];
        short8v b1 = *(const short8v*)&Bs[wc + 16 + lrow][k0];
        acc00 = __builtin_amdgcn_mfma_f32_16x16x32_bf16(a0, b0, acc00, 0, 0, 0);
        acc01 = __builtin_amdgcn_mfma_f32_16x16x32_bf16(a0, b1, acc01, 0, 0, 0);
        acc10 = __builtin_amdgcn_mfma_f32_16x16x32_bf16(a1, b0, acc10, 0, 0, 0);
        acc11 = __builtin_amdgcn_mfma_f32_16x16x32_bf16(a1, b1, acc11, 0, 0, 0);
    }

#pragma unroll
    for (int rt = 0; rt < 2; rt++) {
        const f32x4 va = rt ? acc10 : acc00;
        const f32x4 vb = rt ? acc11 : acc01;
#pragma unroll
        for (int reg = 0; reg < 4; reg++) {
            int row = rbase + wr + rt * 16 + lkg * 4 + reg;
            if (row < N) {
                float dv = dis[row];
                Y[(size_t)row * 128 + cbase + wc + lrow] = f2bf(va[reg] * dv);
                Y[(size_t)row * 128 + cbase + wc + 16 + lrow] = f2bf(vb[reg] * dv);
            }
        }
    }
}

// ---------------- final GEMM: out[G,256] = P[G,128] @ W3 + b3 (empty-graph guard) ----------------
__global__ __launch_bounds__(256) void k_gemm_final(const float* __restrict__ X,
                                                    const float* __restrict__ W,
                                                    const float* __restrict__ bias,
                                                    const int* __restrict__ goff,
                                                    float* __restrict__ out, int G) {
    __shared__ float xt[128][64];
    __shared__ float wt[128][64];
    const int t = threadIdx.x;
    const int rbase = blockIdx.x * 64;
    const int cbase = blockIdx.y * 64;

    for (int it = 0; it < 8; it++) {
        int idx = t + it * 256;
        int k4 = idx >> 6;
        int r = idx & 63;
        int row = rbase + r;
        float4 v = make_float4(0.f, 0.f, 0.f, 0.f);
        if (row < G) v = *(const float4*)(X + (size_t)row * 128 + k4 * 4);
        xt[k4 * 4 + 0][r] = v.x;
        xt[k4 * 4 + 1][r] = v.y;
        xt[k4 * 4 + 2][r] = v.z;
        xt[k4 * 4 + 3][r] = v.w;
    }
    for (int it = 0; it < 8; it++) {
        int idx = t + it * 256;
        int k = idx >> 4;
        int c4 = (idx & 15) * 4;
        *(float4*)&wt[k][c4] = *(const float4*)(W + (size_t)k * 256 + cbase + c4);
    }
    __syncthreads();

    const int r0 = (t >> 4) * 4;
    const int c0 = (t & 15) * 4;
    float acc[4][4];
#pragma unroll
    for (int i = 0; i < 4; i++)
#pragma unroll
        for (int j = 0; j < 4; j++) acc[i][j] = 0.0f;

#pragma unroll 4
    for (int k = 0; k < 128; k++) {
        float4 a = *(const float4*)&xt[k][r0];
        float4 b = *(const float4*)&wt[k][c0];
        const float av[4] = {a.x, a.y, a.z, a.w};
        const float bv[4] = {b.x, b.y, b.z, b.w};
#pragma unroll
        for (int i = 0; i < 4; i++)
#pragma unroll
            for (int j = 0; j < 4; j++) acc[i][j] += av[i] * bv[j];
    }

#pragma unroll
    for (int i = 0; i < 4; i++) {
        int row = rbase + r0 + i;
        if (row < G) {
            bool empty = (goff[row + 1] == goff[row]);
            float4 o;
            o.x = empty ? 0.f : acc[i][0] + bias[cbase + c0 + 0];
            o.y = empty ? 0.f : acc[i][1] + bias[cbase + c0 + 1];
            o.z = empty ? 0.f : acc[i][2] + bias[cbase + c0 + 2];
            o.w = empty ? 0.f : acc[i][3] + bias[cbase + c0 + 3];
            *(float4*)(out + (size_t)row * 256 + cbase + c0) = o;
        }
    }
}

// ---------------- CSR aggregation (H pre-scaled by dis), 8-deep MLP, fused BN stats ----------------
template <bool STATS>
__global__ __launch_bounds__(256) void k_aggr2(const unsigned short* __restrict__ H,
                                               const int* __restrict__ esrc,
                                               const int* __restrict__ roff,
                                               const float* __restrict__ dis,
                                               const float* __restrict__ bias,
                                               float* __restrict__ out, int N,
                                               float* __restrict__ partial) {
    constexpr int M = 128;
    constexpr int GSZ = 16;
    constexpr int GPB = 16;
    const int nGroups = gridDim.x * GPB;
    const int gid = blockIdx.x * GPB + threadIdx.x / GSZ;
    const int lane = threadIdx.x % GSZ;
    const int c8 = lane * 8;
    const float4 bva = *(const float4*)(bias + c8);
    const float4 bvb = *(const float4*)(bias + c8 + 4);

    float ss[8], sq[8];
    if (STATS) {
#pragma unroll
        for (int k = 0; k < 8; k++) { ss[k] = 0.f; sq[k] = 0.f; }
    }

    for (int n = gid; n < N; n += nGroups) {
        const int rs = roff[n], re = roff[n + 1];
        float acc[8];
#pragma unroll
        for (int j = 0; j < 8; j++) acc[j] = 0.0f;

        int e = rs;
        for (; e + 8 <= re; e += 8) {
            int sid[8];
#pragma unroll
            for (int q = 0; q < 8; q++) sid[q] = esrc[e + q];
            int4 hv[8];
#pragma unroll
            for (int q = 0; q < 8; q++)
                hv[q] = *(const int4*)(H + (size_t)sid[q] * M + c8);
#pragma unroll
            for (int q = 0; q < 8; q++) {
                const int w[4] = {hv[q].x, hv[q].y, hv[q].z, hv[q].w};
#pragma unroll
                for (int k = 0; k < 4; k++) {
                    acc[2 * k + 0] += lo16(w[k]);
                    acc[2 * k + 1] += hi16(w[k]);
                }
            }
        }
        if (e + 4 <= re) {
            int sid[4];
#pragma unroll
            for (int q = 0; q < 4; q++) sid[q] = esrc[e + q];
            int4 hv[4];
#pragma unroll
            for (int q = 0; q < 4; q++)
                hv[q] = *(const int4*)(H + (size_t)sid[q] * M + c8);
#pragma unroll
            for (int q = 0; q < 4; q++) {
                const int w[4] = {hv[q].x, hv[q].y, hv[q].z, hv[q].w};
#pragma unroll
                for (int k = 0; k < 4; k++) {
                    acc[2 * k + 0] += lo16(w[k]);
                    acc[2 * k + 1] += hi16(w[k]);
                }
            }
            e += 4;
        }
        for (; e < re; e++) {
            const int s = esrc[e];
            const int4 h = *(const int4*)(H + (size_t)s * M + c8);
            const int w[4] = {h.x, h.y, h.z, h.w};
#pragma unroll
            for (int k = 0; k < 4; k++) {
                acc[2 * k + 0] += lo16(w[k]);
                acc[2 * k + 1] += hi16(w[k]);
            }
        }
        {
            const int4 h = *(const int4*)(H + (size_t)n * M + c8);
            const int w[4] = {h.x, h.y, h.z, h.w};
#pragma unroll
            for (int k = 0; k < 4; k++) {
                acc[2 * k + 0] += lo16(w[k]);
                acc[2 * k + 1] += hi16(w[k]);
            }
        }
        const float dn = dis[n];
        float ov[8];
#pragma unroll
        for (int k = 0; k < 8; k++) {
            float b = (k < 4) ? (&bva.x)[k] : (&bvb.x)[k - 4];
            ov[k] = acc[k] * dn + b;
            if (STATS) { ss[k] += ov[k]; sq[k] += ov[k] * ov[k]; }
        }
        float4 oa = make_float4(ov[0], ov[1], ov[2], ov[3]);
        float4 ob = make_float4(ov[4], ov[5], ov[6], ov[7]);
        *(float4*)(out + (size_t)n * M + c8) = oa;
        *(float4*)(out + (size_t)n * M + c8 + 4) = ob;
    }

    if (STATS) {
        __shared__ float ls[GPB][256];
        const int g = threadIdx.x / GSZ;
#pragma unroll
        for (int k = 0; k < 8; k++) {
            ls[g][c8 + k] = ss[k];
            ls[g][128 + c8 + k] = sq[k];
        }
        __syncthreads();
        const int f = threadIdx.x;
        float v = 0.f;
#pragma unroll
        for (int gg = 0; gg < GPB; gg++) v += ls[gg][f];
        partial[(size_t)blockIdx.x * 256 + f] = v;
    }
}

// ---------------- reduce partial stats ----------------
__global__ __launch_bounds__(256) void k_redstats(const float* __restrict__ partial,
                                                  float* __restrict__ sums,
                                                  float* __restrict__ sumsq, int nblk) {
    const int f = blockIdx.x;
    const int t = threadIdx.x;
    float v = 0.f;
    for (int b = t; b < nblk; b += 256) v += partial[(size_t)b * 256 + f];
    __shared__ float sh[256];
    sh[t] = v;
    __syncthreads();
    for (int d = 128; d > 0; d >>= 1) {
        if (t < d) sh[t] += sh[t + d];
        __syncthreads();
    }
    if (t == 0) {
        if (f < 128) sums[f] = sh[0];
        else sumsq[f - 128] = sh[0];
    }
}

// ---------------- BN+ReLU -> bf16 cast, pre-scaled by dis ----------------
__global__ void k_bncast(const float* __restrict__ X, const float* __restrict__ sums,
                         const float* __restrict__ sumsq, const float* __restrict__ g,
                         const float* __restrict__ be, const float* __restrict__ dis,
                         unsigned short* __restrict__ Y, long long total4, float inv_n) {
    long long idx = (long long)blockIdx.x * blockDim.x + threadIdx.x;
    if (idx >= total4) return;
    int c4 = ((int)idx & 31) << 2;
    const float dn = dis[(int)(idx >> 5)];
    float4 v = *(const float4*)(X + idx * 4);
    float o[4] = {v.x, v.y, v.z, v.w};
    ushort4 r;
    unsigned short* rp = &r.x;
#pragma unroll
    for (int j = 0; j < 4; j++) {
        int c = c4 + j;
        float mean = sums[c] * inv_n;
        float var = sumsq[c] * inv_n - mean * mean;
        float sc = rsqrtf(var + BN_EPS) * g[c];
        rp[j] = f2bf(fmaxf((o[j] - mean) * sc + be[c], 0.0f) * dn);
    }
    *(ushort4*)(Y + idx * 4) = r;
}

// ---------------- segmented mean pool (batch sorted) ----------------
__global__ void k_pool_seg(const float* __restrict__ H, const int* __restrict__ goff,
                           float* __restrict__ out) {
    const int gr = blockIdx.x;
    const int c = threadIdx.x;  // 128
    const int s = goff[gr], e = goff[gr + 1];
    float acc = 0.0f;
    for (int i = s; i < e; i++) acc += H[(size_t)i * 128 + c];
    out[(size_t)gr * 128 + c] = acc / fmaxf((float)(e - s), 1.0f);
}

extern "C" void kernel_launch(void* const* d_in, const int* in_sizes, int n_in,
                              void* d_out, int out_size, void* d_ws, size_t ws_size,
                              hipStream_t stream) {
    const float* x     = (const float*)d_in[0];
    const int*   ei    = (const int*)d_in[1];
    const int*   batch = (const int*)d_in[2];
    const float* W1 = (const float*)d_in[3];
    const float* b1 = (const float*)d_in[4];
    const float* W2 = (const float*)d_in[5];
    const float* b2 = (const float*)d_in[6];
    const float* W3 = (const float*)d_in[7];
    const float* b3 = (const float*)d_in[8];
    const float* g1 = (const float*)d_in[9];
    const float* be1 = (const float*)d_in[10];
    const float* g2 = (const float*)d_in[11];
    const float* be2 = (const float*)d_in[12];
    float* out = (float*)d_out;

    const int N = in_sizes[2];
    const int E = in_sizes[1] / 2;
    const int G = out_size / 256;
    const int* src = ei;
    const int* tgt = ei + E;

    char* ws = (char*)d_ws;
    auto take = [&](size_t bytes) {
        char* p = ws;
        ws += (bytes + 255) & ~(size_t)255;
        return p;
    };
    float*          bufB   = (float*)take((size_t)N * 128 * 4);
    unsigned short* bufH   = (unsigned short*)take((size_t)N * 128 * 2);
    float*          P      = (float*)take((size_t)G * 128 * 4);
    float*          dis    = (float*)take((size_t)N * 4);
    float*          sums   = (float*)take(512 * 4);
    float*          sumsq  = sums + 128;
    float*          zbias  = (float*)take(128 * 4);
    float*          partial= (float*)take((size_t)AGG_BLOCKS * 256 * 4);
    int*            ncnt   = (int*)take((size_t)N * 4);
    int*            roff   = (int*)take((size_t)(N + 1) * 4);
    int*            cursor = (int*)take((size_t)N * 4);
    int*            esrc   = (int*)take((size_t)E * 4);
    int*            gcnt   = (int*)take((size_t)G * 4);
    int*            goff   = (int*)take((size_t)(G + 1) * 4);
    int*            bsumN  = (int*)take(256 * 4);
    int*            bsumG  = (int*)take(256 * 4);

    const int B = 256;
    const int nbN = cdiv(N, SCAN_CHUNK);
    const int nbG = cdiv(G, SCAN_CHUNK);

    // ---- CSR build prologue ----
    hipMemsetAsync(ncnt, 0, (size_t)N * 4, stream);
    hipMemsetAsync(gcnt, 0, (size_t)G * 4, stream);
    hipMemsetAsync(zbias, 0, 128 * 4, stream);
    k_hist2<<<cdiv(max(E, N), B), B, 0, stream>>>(tgt, ncnt, E, batch, gcnt, N);
    k_scan_blk<<<nbN, B, 0, stream>>>(ncnt, bsumN, N);
    k_scan_bsum<<<1, B, 0, stream>>>(bsumN, roff, nbN, N);
    k_scan_out<<<nbN, B, 0, stream>>>(ncnt, bsumN, roff, N, dis, cursor);
    k_scan_blk<<<nbG, B, 0, stream>>>(gcnt, bsumG, G);
    k_scan_bsum<<<1, B, 0, stream>>>(bsumG, goff, nbG, G);
    k_scan_out<<<nbG, B, 0, stream>>>(gcnt, bsumG, goff, G, nullptr, nullptr);

    // ---- fused: CSR fill + layer-1 GEMM (independent, co-resident) ----
    const int nbx = cdiv(N, 64);
    const int GB = nbx * 2;
    const int FB = cdiv(E, B);
    k_fill_gemm<<<GB + FB, B, 0, stream>>>(x, W1, bufH, N, dis, GB, nbx,
                                           src, tgt, cursor, esrc, E);

    long long t4_128 = (long long)N * 32;

    // ---- layer 1 aggregation (+stats) ----
    k_aggr2<true><<<AGG_BLOCKS, B, 0, stream>>>(bufH, esrc, roff, dis, b1, bufB, N, partial);
    k_redstats<<<256, B, 0, stream>>>(partial, sums, sumsq, AGG_BLOCKS);

    // ---- layer 2 (BN1 fused into MFMA staging) ----
    k_gemm_mfma_bn<<<dim3(nbx, 2), B, 0, stream>>>(bufB, W2, bufH, N, dis,
                                                   sums, sumsq, g1, be1, 1.0f / N);
    k_aggr2<true><<<AGG_BLOCKS, B, 0, stream>>>(bufH, esrc, roff, dis, b2, bufB, N, partial);
    k_redstats<<<256, B, 0, stream>>>(partial, sums, sumsq, AGG_BLOCKS);

    // ---- layer 3: BN2+ReLU+dis cast -> aggregate 128-dim -> pool -> small GEMM ----
    k_bncast<<<cdiv(t4_128, B), B, 0, stream>>>(bufB, sums, sumsq, g2, be2, dis, bufH,
                                                t4_128, 1.0f / N);
    k_aggr2<false><<<AGG_BLOCKS, B, 0, stream>>>(bufH, esrc, roff, dis, zbias, bufB, N, nullptr);
    k_pool_seg<<<G, 128, 0, stream>>>(bufB, goff, P);
    k_gemm_final<<<dim3(cdiv(G, 64), 4), B, 0, stream>>>(P, W3, b3, goff, out, G);
}

// Round 9
// 406.749 us; speedup vs baseline: 2.0512x; 1.3119x over previous
//
#include <hip/hip_runtime.h>
#include <hip/hip_bf16.h>

#define BN_EPS 1e-5f
#define SCAN_CHUNK 2048  // 256 threads * 8 elems
#define AGG_BLOCKS 2048
#define BSHIFT 9         // bucket = tgt >> 9 (512 nodes/bucket)
#define BUCKN 512
#define NBP 256          // padded buckets per hcnt row (requires nbuck <= 256)
#define CB 256           // scatter blocks

static inline int cdiv(long long a, long long b) { return (int)((a + b - 1) / b); }

typedef __attribute__((ext_vector_type(8))) short short8v;
typedef __attribute__((ext_vector_type(4))) float f32x4;

__device__ __forceinline__ float lo16(int u) {
    return __uint_as_float(((unsigned int)u) << 16);
}
__device__ __forceinline__ float hi16(int u) {
    return __uint_as_float(((unsigned int)u) & 0xffff0000u);
}
__device__ __forceinline__ unsigned short f2bf(float f) {
    unsigned int b = __float_as_uint(f);
    b += 0x7FFFu + ((b >> 16) & 1u);  // RNE
    return (unsigned short)(b >> 16);
}

// ---------------- pass A: per-block bucket histogram (LDS, no global atomics) ----------------
__global__ __launch_bounds__(256) void k_bhist(const int* __restrict__ tgt,
                                               int* __restrict__ hcnt, int E, int tile,
                                               int nbuck) {
    __shared__ int lh[NBP];
    const int t = threadIdx.x;
    lh[t] = 0;
    __syncthreads();
    const int base = blockIdx.x * tile;
    const int end = min(base + tile, E);
    for (int i = base + t; i < end; i += 256)
        atomicAdd(&lh[tgt[i] >> BSHIFT], 1);
    __syncthreads();
    if (t < nbuck) hcnt[blockIdx.x * NBP + t] = lh[t];
}

// ---------------- B1: per-bucket exclusive scan across blocks (in place) ----------------
__global__ __launch_bounds__(256) void k_bscan(int* __restrict__ hcnt,
                                               int* __restrict__ btot) {
    const int bucket = blockIdx.x;
    const int t = threadIdx.x;  // block index
    __shared__ int sh[256];
    int v = hcnt[t * NBP + bucket];
    sh[t] = v;
    __syncthreads();
    for (int d = 1; d < 256; d <<= 1) {
        int u = (t >= d) ? sh[t - d] : 0;
        __syncthreads();
        sh[t] += u;
        __syncthreads();
    }
    hcnt[t * NBP + bucket] = sh[t] - v;  // exclusive
    if (t == 255) btot[bucket] = sh[255];
}

// ---------------- B2: exclusive scan of bucket totals -> bbase[nbuck+1] ----------------
__global__ __launch_bounds__(256) void k_scan_small(const int* __restrict__ btot,
                                                    int* __restrict__ bbase, int nb) {
    const int t = threadIdx.x;
    __shared__ int sh[256];
    int v = (t < nb) ? btot[t] : 0;
    sh[t] = v;
    __syncthreads();
    for (int d = 1; d < 256; d <<= 1) {
        int u = (t >= d) ? sh[t - d] : 0;
        __syncthreads();
        sh[t] += u;
        __syncthreads();
    }
    if (t < nb) bbase[t] = sh[t] - v;
    if (t == nb) bbase[nb] = sh[255];
    if (t == 255 && nb <= 255) bbase[nb] = sh[255];
}

// ---------------- pass C: scatter pairs into bucket-grouped order (LDS cursors) ----------------
__global__ __launch_bounds__(256) void k_bscatter2(const int* __restrict__ src,
                                                   const int* __restrict__ tgt,
                                                   const int* __restrict__ hcnt,
                                                   const int* __restrict__ bbase,
                                                   int2* __restrict__ pairs, int E,
                                                   int tile, int nbuck) {
    __shared__ int cur[NBP];
    const int t = threadIdx.x;
    if (t < nbuck) cur[t] = bbase[t] + hcnt[blockIdx.x * NBP + t];
    __syncthreads();
    const int base = blockIdx.x * tile;
    const int end = min(base + tile, E);
    for (int i = base + t; i < end; i += 256) {
        int s = src[i];
        int tg = tgt[i];
        int p = atomicAdd(&cur[tg >> BSHIFT], 1);
        pairs[p] = make_int2(s, tg);
    }
}

// ---------------- 2a: per-bucket node histogram -> ncnt (coalesced, no global atomics) ----------------
__global__ __launch_bounds__(256) void k_bucket_ncnt(const int2* __restrict__ pairs,
                                                     const int* __restrict__ bbase,
                                                     int* __restrict__ ncnt, int N) {
    __shared__ int cnt[BUCKN];
    const int b = blockIdx.x;
    const int t = threadIdx.x;
    const int nb0 = b * BUCKN;
#pragma unroll
    for (int k = t; k < BUCKN; k += 256) cnt[k] = 0;
    __syncthreads();
    const int lo = bbase[b], hi = bbase[b + 1];
    for (int p = lo + t; p < hi; p += 256)
        atomicAdd(&cnt[pairs[p].y - nb0], 1);
    __syncthreads();
#pragma unroll
    for (int k = t; k < BUCKN; k += 256) {
        int node = nb0 + k;
        if (node < N) ncnt[node] = cnt[k];
    }
}

// ---------------- hierarchical scan over N: pass 1 ----------------
__global__ __launch_bounds__(256) void k_scan_blk(const int* __restrict__ cnt,
                                                  int* __restrict__ bsum, int n) {
    const int t = threadIdx.x;
    const int base = blockIdx.x * SCAN_CHUNK + t * 8;
    int s = 0;
    if (base + 8 <= n) {
        int4 a = *(const int4*)(cnt + base);
        int4 b = *(const int4*)(cnt + base + 4);
        s = a.x + a.y + a.z + a.w + b.x + b.y + b.z + b.w;
    } else {
#pragma unroll
        for (int j = 0; j < 8; j++) {
            int i = base + j;
            if (i < n) s += cnt[i];
        }
    }
    __shared__ int red[256];
    red[t] = s;
    __syncthreads();
    for (int d = 128; d > 0; d >>= 1) {
        if (t < d) red[t] += red[t + d];
        __syncthreads();
    }
    if (t == 0) bsum[blockIdx.x] = red[0];
}

// ---------------- scan pass 2 ----------------
__global__ __launch_bounds__(256) void k_scan_bsum(int* __restrict__ bsum,
                                                   int* __restrict__ off, int nb, int n) {
    const int t = threadIdx.x;
    __shared__ int sh[256];
    int v = (t < nb) ? bsum[t] : 0;
    sh[t] = v;
    __syncthreads();
    for (int d = 1; d < 256; d <<= 1) {
        int u = (t >= d) ? sh[t - d] : 0;
        __syncthreads();
        sh[t] += u;
        __syncthreads();
    }
    if (t < nb) bsum[t] = sh[t] - v;
    if (t == 255) off[n] = sh[255];
}

// ---------------- scan pass 3: offsets + dis + cursor ----------------
__global__ __launch_bounds__(256) void k_scan_out(const int* __restrict__ cnt,
                                                  const int* __restrict__ bsum,
                                                  int* __restrict__ off, int n,
                                                  float* __restrict__ dis,
                                                  int* __restrict__ cursor) {
    const int t = threadIdx.x;
    const int base = blockIdx.x * SCAN_CHUNK + t * 8;
    int c[8], loc[8];
    int s = 0;
#pragma unroll
    for (int j = 0; j < 8; j++) {
        int i = base + j;
        c[j] = (i < n) ? cnt[i] : 0;
        loc[j] = s;
        s += c[j];
    }
    __shared__ int sh[256];
    sh[t] = s;
    __syncthreads();
    for (int d = 1; d < 256; d <<= 1) {
        int u = (t >= d) ? sh[t - d] : 0;
        __syncthreads();
        sh[t] += u;
        __syncthreads();
    }
    const int texcl = sh[t] - s + bsum[blockIdx.x];
#pragma unroll
    for (int j = 0; j < 8; j++) {
        int i = base + j;
        if (i < n) {
            int o = texcl + loc[j];
            off[i] = o;
            if (cursor) cursor[i] = o;
            if (dis) dis[i] = rsqrtf((float)c[j] + 1.0f);
        }
    }
}

// ---------------- 2b: per-bucket fill (L2-local cursors + esrc window) ----------------
__global__ __launch_bounds__(256) void k_bucket_fill(const int2* __restrict__ pairs,
                                                     const int* __restrict__ bbase,
                                                     int* __restrict__ cursor,
                                                     int* __restrict__ esrc) {
    const int b = blockIdx.x;
    const int t = threadIdx.x;
    const int lo = bbase[b], hi = bbase[b + 1];
    for (int p = lo + t; p < hi; p += 256) {
        int2 e = pairs[p];
        int q = atomicAdd(&cursor[e.y], 1);
        esrc[q] = e.x;
    }
}

// ---------------- goff directly from sorted batch ----------------
__global__ void k_goff(const int* __restrict__ batch, int* __restrict__ goff,
                       int N, int G) {
    int i = blockIdx.x * blockDim.x + threadIdx.x;
    if (i >= N) return;
    int cur = batch[i];
    int prev = (i == 0) ? -1 : batch[i - 1];
    for (int g = prev + 1; g <= cur; g++) goff[g] = i;
    if (i == N - 1) {
        for (int g = cur + 1; g <= G; g++) goff[g] = N;
    }
}

// ---------------- MFMA GEMM: Ybf16[N,128] = (BN?(X) @ W[128,128]) * dis[row] ----------------
template <bool BN>
__global__ __launch_bounds__(256) void k_gemm_mfma(const float* __restrict__ X,
                                                   const float* __restrict__ W,
                                                   unsigned short* __restrict__ Y, int N,
                                                   const float* __restrict__ dis,
                                                   const float* __restrict__ sums,
                                                   const float* __restrict__ sumsq,
                                                   const float* __restrict__ g,
                                                   const float* __restrict__ be,
                                                   float inv_n) {
    __shared__ unsigned short As[64][136];
    __shared__ unsigned short Bs[64][136];
    const int t = threadIdx.x;
    const int rbase = blockIdx.x * 64;
    const int cbase = blockIdx.y * 64;

    for (int it = 0; it < 8; it++) {
        int idx = t + it * 256;
        int r = idx >> 5;
        int k4 = (idx & 31) * 4;
        int row = rbase + r;
        float4 v = make_float4(0.f, 0.f, 0.f, 0.f);
        if (row < N) v = *(const float4*)(X + (size_t)row * 128 + k4);
        float o[4] = {v.x, v.y, v.z, v.w};
        if (BN) {
#pragma unroll
            for (int j = 0; j < 4; j++) {
                int c = k4 + j;
                float mean = sums[c] * inv_n;
                float var = sumsq[c] * inv_n - mean * mean;
                float sc = rsqrtf(var + BN_EPS) * g[c];
                o[j] = fmaxf((o[j] - mean) * sc + be[c], 0.0f);
            }
        }
        ushort4 u;
        u.x = f2bf(o[0]); u.y = f2bf(o[1]); u.z = f2bf(o[2]); u.w = f2bf(o[3]);
        *(ushort4*)&As[r][k4] = u;
    }
    for (int it = 0; it < 8; it++) {
        int idx = t + it * 256;
        int k = idx >> 4;
        int c4 = (idx & 15) * 4;
        float4 v = *(const float4*)(W + (size_t)k * 128 + cbase + c4);
        Bs[c4 + 0][k] = f2bf(v.x);
        Bs[c4 + 1][k] = f2bf(v.y);
        Bs[c4 + 2][k] = f2bf(v.z);
        Bs[c4 + 3][k] = f2bf(v.w);
    }
    __syncthreads();

    const int wid = t >> 6;
    const int lane = t & 63;
    const int wr = (wid >> 1) * 32;
    const int wc = (wid & 1) * 32;
    const int lrow = lane & 15;
    const int lkg = lane >> 4;

    f32x4 acc00 = 0, acc01 = 0, acc10 = 0, acc11 = 0;
#pragma unroll
    for (int kk = 0; kk < 4; kk++) {
        const int k0 = kk * 32 + lkg * 8;
        short8v a0 = *(const short8v*)&As[wr + lrow][k0];
        short8v a1 = *(const short8v*)&As[wr + 16 + lrow][k0];
        short8v b0 = *(const short8v*)&Bs[wc + lrow][k0];
        short8v b1 = *(const short8v*)&Bs[wc + 16 + lrow][k0];
        acc00 = __builtin_amdgcn_mfma_f32_16x16x32_bf16(a0, b0, acc00, 0, 0, 0);
        acc01 = __builtin_amdgcn_mfma_f32_16x16x32_bf16(a0, b1, acc01, 0, 0, 0);
        acc10 = __builtin_amdgcn_mfma_f32_16x16x32_bf16(a1, b0, acc10, 0, 0, 0);
        acc11 = __builtin_amdgcn_mfma_f32_16x16x32_bf16(a1, b1, acc11, 0, 0, 0);
    }

#pragma unroll
    for (int rt = 0; rt < 2; rt++) {
        const f32x4 va = rt ? acc10 : acc00;
        const f32x4 vb = rt ? acc11 : acc01;
#pragma unroll
        for (int reg = 0; reg < 4; reg++) {
            int row = rbase + wr + rt * 16 + lkg * 4 + reg;
            if (row < N) {
                float dv = dis[row];
                Y[(size_t)row * 128 + cbase + wc + lrow] = f2bf(va[reg] * dv);
                Y[(size_t)row * 128 + cbase + wc + 16 + lrow] = f2bf(vb[reg] * dv);
            }
        }
    }
}

// ---------------- final GEMM: out[G,256] = P[G,128] @ W3 + b3 (empty-graph guard) ----------------
__global__ __launch_bounds__(256) void k_gemm_final(const float* __restrict__ X,
                                                    const float* __restrict__ W,
                                                    const float* __restrict__ bias,
                                                    const int* __restrict__ goff,
                                                    float* __restrict__ out, int G) {
    __shared__ float xt[128][64];
    __shared__ float wt[128][64];
    const int t = threadIdx.x;
    const int rbase = blockIdx.x * 64;
    const int cbase = blockIdx.y * 64;

    for (int it = 0; it < 8; it++) {
        int idx = t + it * 256;
        int k4 = idx >> 6;
        int r = idx & 63;
        int row = rbase + r;
        float4 v = make_float4(0.f, 0.f, 0.f, 0.f);
        if (row < G) v = *(const float4*)(X + (size_t)row * 128 + k4 * 4);
        xt[k4 * 4 + 0][r] = v.x;
        xt[k4 * 4 + 1][r] = v.y;
        xt[k4 * 4 + 2][r] = v.z;
        xt[k4 * 4 + 3][r] = v.w;
    }
    for (int it = 0; it < 8; it++) {
        int idx = t + it * 256;
        int k = idx >> 4;
        int c4 = (idx & 15) * 4;
        *(float4*)&wt[k][c4] = *(const float4*)(W + (size_t)k * 256 + cbase + c4);
    }
    __syncthreads();

    const int r0 = (t >> 4) * 4;
    const int c0 = (t & 15) * 4;
    float acc[4][4];
#pragma unroll
    for (int i = 0; i < 4; i++)
#pragma unroll
        for (int j = 0; j < 4; j++) acc[i][j] = 0.0f;

#pragma unroll 4
    for (int k = 0; k < 128; k++) {
        float4 a = *(const float4*)&xt[k][r0];
        float4 b = *(const float4*)&wt[k][c0];
        const float av[4] = {a.x, a.y, a.z, a.w};
        const float bv[4] = {b.x, b.y, b.z, b.w};
#pragma unroll
        for (int i = 0; i < 4; i++)
#pragma unroll
            for (int j = 0; j < 4; j++) acc[i][j] += av[i] * bv[j];
    }

#pragma unroll
    for (int i = 0; i < 4; i++) {
        int row = rbase + r0 + i;
        if (row < G) {
            bool empty = (goff[row + 1] == goff[row]);
            float4 o;
            o.x = empty ? 0.f : acc[i][0] + bias[cbase + c0 + 0];
            o.y = empty ? 0.f : acc[i][1] + bias[cbase + c0 + 1];
            o.z = empty ? 0.f : acc[i][2] + bias[cbase + c0 + 2];
            o.w = empty ? 0.f : acc[i][3] + bias[cbase + c0 + 3];
            *(float4*)(out + (size_t)row * 256 + cbase + c0) = o;
        }
    }
}

// ---------------- CSR aggregation (H pre-scaled by dis), 8-deep MLP, fused BN stats ----------------
template <bool STATS>
__global__ __launch_bounds__(256) void k_aggr2(const unsigned short* __restrict__ H,
                                               const int* __restrict__ esrc,
                                               const int* __restrict__ roff,
                                               const float* __restrict__ dis,
                                               const float* __restrict__ bias,
                                               float* __restrict__ out, int N,
                                               float* __restrict__ partial) {
    constexpr int M = 128;
    constexpr int GSZ = 16;
    constexpr int GPB = 16;
    const int nGroups = gridDim.x * GPB;
    const int gid = blockIdx.x * GPB + threadIdx.x / GSZ;
    const int lane = threadIdx.x % GSZ;
    const int c8 = lane * 8;
    const float4 bva = *(const float4*)(bias + c8);
    const float4 bvb = *(const float4*)(bias + c8 + 4);

    float ss[8], sq[8];
    if (STATS) {
#pragma unroll
        for (int k = 0; k < 8; k++) { ss[k] = 0.f; sq[k] = 0.f; }
    }

    for (int n = gid; n < N; n += nGroups) {
        const int rs = roff[n], re = roff[n + 1];
        float acc[8];
#pragma unroll
        for (int j = 0; j < 8; j++) acc[j] = 0.0f;

        int e = rs;
        for (; e + 8 <= re; e += 8) {
            int sid[8];
#pragma unroll
            for (int q = 0; q < 8; q++) sid[q] = esrc[e + q];
            int4 hv[8];
#pragma unroll
            for (int q = 0; q < 8; q++)
                hv[q] = *(const int4*)(H + (size_t)sid[q] * M + c8);
#pragma unroll
            for (int q = 0; q < 8; q++) {
                const int w[4] = {hv[q].x, hv[q].y, hv[q].z, hv[q].w};
#pragma unroll
                for (int k = 0; k < 4; k++) {
                    acc[2 * k + 0] += lo16(w[k]);
                    acc[2 * k + 1] += hi16(w[k]);
                }
            }
        }
        if (e + 4 <= re) {
            int sid[4];
#pragma unroll
            for (int q = 0; q < 4; q++) sid[q] = esrc[e + q];
            int4 hv[4];
#pragma unroll
            for (int q = 0; q < 4; q++)
                hv[q] = *(const int4*)(H + (size_t)sid[q] * M + c8);
#pragma unroll
            for (int q = 0; q < 4; q++) {
                const int w[4] = {hv[q].x, hv[q].y, hv[q].z, hv[q].w};
#pragma unroll
                for (int k = 0; k < 4; k++) {
                    acc[2 * k + 0] += lo16(w[k]);
                    acc[2 * k + 1] += hi16(w[k]);
                }
            }
            e += 4;
        }
        for (; e < re; e++) {
            const int s = esrc[e];
            const int4 h = *(const int4*)(H + (size_t)s * M + c8);
            const int w[4] = {h.x, h.y, h.z, h.w};
#pragma unroll
            for (int k = 0; k < 4; k++) {
                acc[2 * k + 0] += lo16(w[k]);
                acc[2 * k + 1] += hi16(w[k]);
            }
        }
        {
            const int4 h = *(const int4*)(H + (size_t)n * M + c8);
            const int w[4] = {h.x, h.y, h.z, h.w};
#pragma unroll
            for (int k = 0; k < 4; k++) {
                acc[2 * k + 0] += lo16(w[k]);
                acc[2 * k + 1] += hi16(w[k]);
            }
        }
        const float dn = dis[n];
        float ov[8];
#pragma unroll
        for (int k = 0; k < 8; k++) {
            float b = (k < 4) ? (&bva.x)[k] : (&bvb.x)[k - 4];
            ov[k] = acc[k] * dn + b;
            if (STATS) { ss[k] += ov[k]; sq[k] += ov[k] * ov[k]; }
        }
        float4 oa = make_float4(ov[0], ov[1], ov[2], ov[3]);
        float4 ob = make_float4(ov[4], ov[5], ov[6], ov[7]);
        *(float4*)(out + (size_t)n * M + c8) = oa;
        *(float4*)(out + (size_t)n * M + c8 + 4) = ob;
    }

    if (STATS) {
        __shared__ float ls[GPB][256];
        const int g = threadIdx.x / GSZ;
#pragma unroll
        for (int k = 0; k < 8; k++) {
            ls[g][c8 + k] = ss[k];
            ls[g][128 + c8 + k] = sq[k];
        }
        __syncthreads();
        const int f = threadIdx.x;
        float v = 0.f;
#pragma unroll
        for (int gg = 0; gg < GPB; gg++) v += ls[gg][f];
        partial[(size_t)blockIdx.x * 256 + f] = v;
    }
}

// ---------------- reduce partial stats ----------------
__global__ __launch_bounds__(256) void k_redstats(const float* __restrict__ partial,
                                                  float* __restrict__ sums,
                                                  float* __restrict__ sumsq, int nblk) {
    const int f = blockIdx.x;
    const int t = threadIdx.x;
    float v = 0.f;
    for (int b = t; b < nblk; b += 256) v += partial[(size_t)b * 256 + f];
    __shared__ float sh[256];
    sh[t] = v;
    __syncthreads();
    for (int d = 128; d > 0; d >>= 1) {
        if (t < d) sh[t] += sh[t + d];
        __syncthreads();
    }
    if (t == 0) {
        if (f < 128) sums[f] = sh[0];
        else sumsq[f - 128] = sh[0];
    }
}

// ---------------- BN+ReLU -> bf16 cast, pre-scaled by dis ----------------
__global__ void k_bncast(const float* __restrict__ X, const float* __restrict__ sums,
                         const float* __restrict__ sumsq, const float* __restrict__ g,
                         const float* __restrict__ be, const float* __restrict__ dis,
                         unsigned short* __restrict__ Y, long long total4, float inv_n) {
    long long idx = (long long)blockIdx.x * blockDim.x + threadIdx.x;
    if (idx >= total4) return;
    int c4 = ((int)idx & 31) << 2;
    const float dn = dis[(int)(idx >> 5)];
    float4 v = *(const float4*)(X + idx * 4);
    float o[4] = {v.x, v.y, v.z, v.w};
    ushort4 r;
    unsigned short* rp = &r.x;
#pragma unroll
    for (int j = 0; j < 4; j++) {
        int c = c4 + j;
        float mean = sums[c] * inv_n;
        float var = sumsq[c] * inv_n - mean * mean;
        float sc = rsqrtf(var + BN_EPS) * g[c];
        rp[j] = f2bf(fmaxf((o[j] - mean) * sc + be[c], 0.0f) * dn);
    }
    *(ushort4*)(Y + idx * 4) = r;
}

// ---------------- segmented mean pool (batch sorted) ----------------
__global__ void k_pool_seg(const float* __restrict__ H, const int* __restrict__ goff,
                           float* __restrict__ out) {
    const int gr = blockIdx.x;
    const int c = threadIdx.x;  // 128
    const int s = goff[gr], e = goff[gr + 1];
    float acc = 0.0f;
    for (int i = s; i < e; i++) acc += H[(size_t)i * 128 + c];
    out[(size_t)gr * 128 + c] = acc / fmaxf((float)(e - s), 1.0f);
}

extern "C" void kernel_launch(void* const* d_in, const int* in_sizes, int n_in,
                              void* d_out, int out_size, void* d_ws, size_t ws_size,
                              hipStream_t stream) {
    const float* x     = (const float*)d_in[0];
    const int*   ei    = (const int*)d_in[1];
    const int*   batch = (const int*)d_in[2];
    const float* W1 = (const float*)d_in[3];
    const float* b1 = (const float*)d_in[4];
    const float* W2 = (const float*)d_in[5];
    const float* b2 = (const float*)d_in[6];
    const float* W3 = (const float*)d_in[7];
    const float* b3 = (const float*)d_in[8];
    const float* g1 = (const float*)d_in[9];
    const float* be1 = (const float*)d_in[10];
    const float* g2 = (const float*)d_in[11];
    const float* be2 = (const float*)d_in[12];
    float* out = (float*)d_out;

    const int N = in_sizes[2];
    const int E = in_sizes[1] / 2;
    const int G = out_size / 256;
    const int* src = ei;
    const int* tgt = ei + E;

    char* ws = (char*)d_ws;
    auto take = [&](size_t bytes) {
        char* p = ws;
        ws += (bytes + 255) & ~(size_t)255;
        return p;
    };
    float*          bufB   = (float*)take((size_t)N * 128 * 4);
    unsigned short* bufH   = (unsigned short*)take((size_t)N * 128 * 2);
    float*          P      = (float*)take((size_t)G * 128 * 4);
    float*          dis    = (float*)take((size_t)N * 4);
    float*          sums   = (float*)take(512 * 4);
    float*          sumsq  = sums + 128;
    float*          zbias  = (float*)take(128 * 4);
    float*          partial= (float*)take((size_t)AGG_BLOCKS * 256 * 4);
    int*            ncnt   = (int*)take((size_t)N * 4);
    int*            roff   = (int*)take((size_t)(N + 1) * 4);
    int*            cursor = (int*)take((size_t)N * 4);
    int*            esrc   = (int*)take((size_t)E * 4);
    int*            goff   = (int*)take((size_t)(G + 1) * 4);
    int*            bsumN  = (int*)take(256 * 4);
    int*            hcnt   = (int*)take((size_t)CB * NBP * 4);
    int*            btot   = (int*)take(NBP * 4);
    int*            bbase  = (int*)take((NBP + 1) * 4);
    int2*           pairs  = (int2*)bufB;  // alias: consumed before bufB's first write

    const int B = 256;
    const int nbN = cdiv(N, SCAN_CHUNK);
    const int nbuck = cdiv(N, BUCKN);     // <= 256 for N <= 131072
    const int tile = cdiv(E, CB);

    hipMemsetAsync(zbias, 0, 128 * 4, stream);

    // ---- CSR build: bucketed counting sort (coalesced, no contended atomics) ----
    k_bhist<<<CB, B, 0, stream>>>(tgt, hcnt, E, tile, nbuck);
    k_bscan<<<nbuck, B, 0, stream>>>(hcnt, btot);
    k_scan_small<<<1, B, 0, stream>>>(btot, bbase, nbuck);
    k_bscatter2<<<CB, B, 0, stream>>>(src, tgt, hcnt, bbase, pairs, E, tile, nbuck);
    k_bucket_ncnt<<<nbuck, B, 0, stream>>>(pairs, bbase, ncnt, N);
    k_scan_blk<<<nbN, B, 0, stream>>>(ncnt, bsumN, N);
    k_scan_bsum<<<1, B, 0, stream>>>(bsumN, roff, nbN, N);
    k_scan_out<<<nbN, B, 0, stream>>>(ncnt, bsumN, roff, N, dis, cursor);
    k_bucket_fill<<<nbuck, B, 0, stream>>>(pairs, bbase, cursor, esrc);
    k_goff<<<cdiv(N, B), B, 0, stream>>>(batch, goff, N, G);

    long long t4_128 = (long long)N * 32;
    const int nbx = cdiv(N, 64);

    // ---- layer 1 ----
    k_gemm_mfma<false><<<dim3(nbx, 2), B, 0, stream>>>(x, W1, bufH, N, dis,
                                                       nullptr, nullptr, nullptr, nullptr, 0.f);
    k_aggr2<true><<<AGG_BLOCKS, B, 0, stream>>>(bufH, esrc, roff, dis, b1, bufB, N, partial);
    k_redstats<<<256, B, 0, stream>>>(partial, sums, sumsq, AGG_BLOCKS);

    // ---- layer 2 (BN1 fused into MFMA staging) ----
    k_gemm_mfma<true><<<dim3(nbx, 2), B, 0, stream>>>(bufB, W2, bufH, N, dis,
                                                      sums, sumsq, g1, be1, 1.0f / N);
    k_aggr2<true><<<AGG_BLOCKS, B, 0, stream>>>(bufH, esrc, roff, dis, b2, bufB, N, partial);
    k_redstats<<<256, B, 0, stream>>>(partial, sums, sumsq, AGG_BLOCKS);

    // ---- layer 3: BN2+ReLU+dis cast -> aggregate 128-dim -> pool -> small GEMM ----
    k_bncast<<<cdiv(t4_128, B), B, 0, stream>>>(bufB, sums, sumsq, g2, be2, dis, bufH,
                                                t4_128, 1.0f / N);
    k_aggr2<false><<<AGG_BLOCKS, B, 0, stream>>>(bufH, esrc, roff, dis, zbias, bufB, N, nullptr);
    k_pool_seg<<<G, 128, 0, stream>>>(bufB, goff, P);
    k_gemm_final<<<dim3(cdiv(G, 64), 4), B, 0, stream>>>(P, W3, b3, goff, out, G);
}

// Round 10
// 387.397 us; speedup vs baseline: 2.1537x; 1.0500x over previous
//
#include <hip/hip_runtime.h>
#include <hip/hip_bf16.h>

#define BN_EPS 1e-5f
#define AGG_BLOCKS 4096
#define BSHIFT 9         // bucket = tgt >> 9 (512 nodes/bucket)
#define BUCKN 512
#define NBP 256          // padded buckets per hcnt row (requires nbuck <= 256)
#define CB 256           // scatter blocks

static inline int cdiv(long long a, long long b) { return (int)((a + b - 1) / b); }

typedef __attribute__((ext_vector_type(8))) short short8v;
typedef __attribute__((ext_vector_type(4))) float f32x4;

__device__ __forceinline__ float lo16(int u) {
    return __uint_as_float(((unsigned int)u) << 16);
}
__device__ __forceinline__ float hi16(int u) {
    return __uint_as_float(((unsigned int)u) & 0xffff0000u);
}
__device__ __forceinline__ unsigned short f2bf(float f) {
    unsigned int b = __float_as_uint(f);
    b += 0x7FFFu + ((b >> 16) & 1u);  // RNE
    return (unsigned short)(b >> 16);
}

// ---------------- pass A: per-block bucket histogram (LDS) ----------------
__global__ __launch_bounds__(256) void k_bhist(const int* __restrict__ tgt,
                                               int* __restrict__ hcnt, int E, int tile,
                                               int nbuck) {
    __shared__ int lh[NBP];
    const int t = threadIdx.x;
    lh[t] = 0;
    __syncthreads();
    const int base = blockIdx.x * tile;
    const int end = min(base + tile, E);
    for (int i = base + t; i < end; i += 256)
        atomicAdd(&lh[tgt[i] >> BSHIFT], 1);
    __syncthreads();
    if (t < nbuck) hcnt[blockIdx.x * NBP + t] = lh[t];
}

// ---------------- B1: per-bucket exclusive scan across blocks ----------------
__global__ __launch_bounds__(256) void k_bscan(int* __restrict__ hcnt,
                                               int* __restrict__ btot) {
    const int bucket = blockIdx.x;
    const int t = threadIdx.x;
    __shared__ int sh[256];
    int v = hcnt[t * NBP + bucket];
    sh[t] = v;
    __syncthreads();
    for (int d = 1; d < 256; d <<= 1) {
        int u = (t >= d) ? sh[t - d] : 0;
        __syncthreads();
        sh[t] += u;
        __syncthreads();
    }
    hcnt[t * NBP + bucket] = sh[t] - v;
    if (t == 255) btot[bucket] = sh[255];
}

// ---------------- B2: scan of bucket totals -> bbase[nbuck+1] ----------------
__global__ __launch_bounds__(256) void k_scan_small(const int* __restrict__ btot,
                                                    int* __restrict__ bbase, int nb) {
    const int t = threadIdx.x;
    __shared__ int sh[256];
    int v = (t < nb) ? btot[t] : 0;
    sh[t] = v;
    __syncthreads();
    for (int d = 1; d < 256; d <<= 1) {
        int u = (t >= d) ? sh[t - d] : 0;
        __syncthreads();
        sh[t] += u;
        __syncthreads();
    }
    if (t < nb) bbase[t] = sh[t] - v;
    if (t == nb) bbase[nb] = sh[255];
    if (t == 255 && nb <= 255) bbase[nb] = sh[255];
}

// ---------------- pass C: scatter pairs into bucket-grouped order ----------------
__global__ __launch_bounds__(256) void k_bscatter2(const int* __restrict__ src,
                                                   const int* __restrict__ tgt,
                                                   const int* __restrict__ hcnt,
                                                   const int* __restrict__ bbase,
                                                   int2* __restrict__ pairs, int E,
                                                   int tile, int nbuck) {
    __shared__ int cur[NBP];
    const int t = threadIdx.x;
    if (t < nbuck) cur[t] = bbase[t] + hcnt[blockIdx.x * NBP + t];
    __syncthreads();
    const int base = blockIdx.x * tile;
    const int end = min(base + tile, E);
    for (int i = base + t; i < end; i += 256) {
        int s = src[i];
        int tg = tgt[i];
        int p = atomicAdd(&cur[tg >> BSHIFT], 1);
        pairs[p] = make_int2(s, tg);
    }
}

// ---------------- pass D: per-bucket CSR finish (count + scan + roff/dis + fill, all LDS) ----------------
__global__ __launch_bounds__(256) void k_bucket_csr(const int2* __restrict__ pairs,
                                                    const int* __restrict__ bbase,
                                                    int* __restrict__ roff,
                                                    float* __restrict__ dis,
                                                    int* __restrict__ esrc,
                                                    int N, int nbuck) {
    __shared__ int cnt[BUCKN];
    __shared__ int cur[BUCKN];
    __shared__ int sh[256];
    const int b = blockIdx.x;
    const int t = threadIdx.x;
    const int nb0 = b * BUCKN;
    cnt[t] = 0;
    cnt[t + 256] = 0;
    __syncthreads();
    const int lo = bbase[b], hi = bbase[b + 1];
    for (int p = lo + t; p < hi; p += 256)
        atomicAdd(&cnt[pairs[p].y - nb0], 1);
    __syncthreads();
    const int c0 = cnt[2 * t], c1 = cnt[2 * t + 1];
    int s = c0 + c1;
    sh[t] = s;
    __syncthreads();
    for (int d = 1; d < 256; d <<= 1) {
        int u = (t >= d) ? sh[t - d] : 0;
        __syncthreads();
        sh[t] += u;
        __syncthreads();
    }
    const int excl = sh[t] - s + lo;  // absolute offset of node nb0+2t
    cur[2 * t] = excl;
    cur[2 * t + 1] = excl + c0;
    const int n0 = nb0 + 2 * t, n1 = n0 + 1;
    if (n0 < N) { roff[n0] = excl; dis[n0] = rsqrtf((float)c0 + 1.0f); }
    if (n1 < N) { roff[n1] = excl + c0; dis[n1] = rsqrtf((float)c1 + 1.0f); }
    if (b == nbuck - 1 && t == 0) roff[N] = hi;
    __syncthreads();
    for (int p = lo + t; p < hi; p += 256) {
        int2 e = pairs[p];
        int q = atomicAdd(&cur[e.y - nb0], 1);
        esrc[q] = e.x;
    }
}

// ---------------- goff directly from sorted batch ----------------
__global__ void k_goff(const int* __restrict__ batch, int* __restrict__ goff,
                       int N, int G) {
    int i = blockIdx.x * blockDim.x + threadIdx.x;
    if (i >= N) return;
    int cur = batch[i];
    int prev = (i == 0) ? -1 : batch[i - 1];
    for (int g = prev + 1; g <= cur; g++) goff[g] = i;
    if (i == N - 1) {
        for (int g = cur + 1; g <= G; g++) goff[g] = N;
    }
}

// ---------------- MFMA GEMM: Ybf16[N,128] = (BN?(X) @ W[128,128]) * dis[row] ----------------
template <bool BN>
__global__ __launch_bounds__(256) void k_gemm_mfma(const float* __restrict__ X,
                                                   const float* __restrict__ W,
                                                   unsigned short* __restrict__ Y, int N,
                                                   const float* __restrict__ dis,
                                                   const float* __restrict__ sums,
                                                   const float* __restrict__ sumsq,
                                                   const float* __restrict__ g,
                                                   const float* __restrict__ be,
                                                   float inv_n) {
    __shared__ unsigned short As[64][136];
    __shared__ unsigned short Bs[64][136];
    const int t = threadIdx.x;
    const int rbase = blockIdx.x * 64;
    const int cbase = blockIdx.y * 64;

    for (int it = 0; it < 8; it++) {
        int idx = t + it * 256;
        int r = idx >> 5;
        int k4 = (idx & 31) * 4;
        int row = rbase + r;
        float4 v = make_float4(0.f, 0.f, 0.f, 0.f);
        if (row < N) v = *(const float4*)(X + (size_t)row * 128 + k4);
        float o[4] = {v.x, v.y, v.z, v.w};
        if (BN) {
#pragma unroll
            for (int j = 0; j < 4; j++) {
                int c = k4 + j;
                float mean = sums[c] * inv_n;
                float var = sumsq[c] * inv_n - mean * mean;
                float sc = rsqrtf(var + BN_EPS) * g[c];
                o[j] = fmaxf((o[j] - mean) * sc + be[c], 0.0f);
            }
        }
        ushort4 u;
        u.x = f2bf(o[0]); u.y = f2bf(o[1]); u.z = f2bf(o[2]); u.w = f2bf(o[3]);
        *(ushort4*)&As[r][k4] = u;
    }
    for (int it = 0; it < 8; it++) {
        int idx = t + it * 256;
        int k = idx >> 4;
        int c4 = (idx & 15) * 4;
        float4 v = *(const float4*)(W + (size_t)k * 128 + cbase + c4);
        Bs[c4 + 0][k] = f2bf(v.x);
        Bs[c4 + 1][k] = f2bf(v.y);
        Bs[c4 + 2][k] = f2bf(v.z);
        Bs[c4 + 3][k] = f2bf(v.w);
    }
    __syncthreads();

    const int wid = t >> 6;
    const int lane = t & 63;
    const int wr = (wid >> 1) * 32;
    const int wc = (wid & 1) * 32;
    const int lrow = lane & 15;
    const int lkg = lane >> 4;

    f32x4 acc00 = 0, acc01 = 0, acc10 = 0, acc11 = 0;
#pragma unroll
    for (int kk = 0; kk < 4; kk++) {
        const int k0 = kk * 32 + lkg * 8;
        short8v a0 = *(const short8v*)&As[wr + lrow][k0];
        short8v a1 = *(const short8v*)&As[wr + 16 + lrow][k0];
        short8v b0 = *(const short8v*)&Bs[wc + lrow][k0];
        short8v b1 = *(const short8v*)&Bs[wc + 16 + lrow][k0];
        acc00 = __builtin_amdgcn_mfma_f32_16x16x32_bf16(a0, b0, acc00, 0, 0, 0);
        acc01 = __builtin_amdgcn_mfma_f32_16x16x32_bf16(a0, b1, acc01, 0, 0, 0);
        acc10 = __builtin_amdgcn_mfma_f32_16x16x32_bf16(a1, b0, acc10, 0, 0, 0);
        acc11 = __builtin_amdgcn_mfma_f32_16x16x32_bf16(a1, b1, acc11, 0, 0, 0);
    }

#pragma unroll
    for (int rt = 0; rt < 2; rt++) {
        const f32x4 va = rt ? acc10 : acc00;
        const f32x4 vb = rt ? acc11 : acc01;
#pragma unroll
        for (int reg = 0; reg < 4; reg++) {
            int row = rbase + wr + rt * 16 + lkg * 4 + reg;
            if (row < N) {
                float dv = dis[row];
                Y[(size_t)row * 128 + cbase + wc + lrow] = f2bf(va[reg] * dv);
                Y[(size_t)row * 128 + cbase + wc + 16 + lrow] = f2bf(vb[reg] * dv);
            }
        }
    }
}

// ---------------- final GEMM: out[G,256] = P[G,128] @ W3 + b3 (empty-graph guard) ----------------
__global__ __launch_bounds__(256) void k_gemm_final(const float* __restrict__ X,
                                                    const float* __restrict__ W,
                                                    const float* __restrict__ bias,
                                                    const int* __restrict__ goff,
                                                    float* __restrict__ out, int G) {
    __shared__ float xt[128][64];
    __shared__ float wt[128][64];
    const int t = threadIdx.x;
    const int rbase = blockIdx.x * 64;
    const int cbase = blockIdx.y * 64;

    for (int it = 0; it < 8; it++) {
        int idx = t + it * 256;
        int k4 = idx >> 6;
        int r = idx & 63;
        int row = rbase + r;
        float4 v = make_float4(0.f, 0.f, 0.f, 0.f);
        if (row < G) v = *(const float4*)(X + (size_t)row * 128 + k4 * 4);
        xt[k4 * 4 + 0][r] = v.x;
        xt[k4 * 4 + 1][r] = v.y;
        xt[k4 * 4 + 2][r] = v.z;
        xt[k4 * 4 + 3][r] = v.w;
    }
    for (int it = 0; it < 8; it++) {
        int idx = t + it * 256;
        int k = idx >> 4;
        int c4 = (idx & 15) * 4;
        *(float4*)&wt[k][c4] = *(const float4*)(W + (size_t)k * 256 + cbase + c4);
    }
    __syncthreads();

    const int r0 = (t >> 4) * 4;
    const int c0 = (t & 15) * 4;
    float acc[4][4];
#pragma unroll
    for (int i = 0; i < 4; i++)
#pragma unroll
        for (int j = 0; j < 4; j++) acc[i][j] = 0.0f;

#pragma unroll 4
    for (int k = 0; k < 128; k++) {
        float4 a = *(const float4*)&xt[k][r0];
        float4 b = *(const float4*)&wt[k][c0];
        const float av[4] = {a.x, a.y, a.z, a.w};
        const float bv[4] = {b.x, b.y, b.z, b.w};
#pragma unroll
        for (int i = 0; i < 4; i++)
#pragma unroll
            for (int j = 0; j < 4; j++) acc[i][j] += av[i] * bv[j];
    }

#pragma unroll
    for (int i = 0; i < 4; i++) {
        int row = rbase + r0 + i;
        if (row < G) {
            bool empty = (goff[row + 1] == goff[row]);
            float4 o;
            o.x = empty ? 0.f : acc[i][0] + bias[cbase + c0 + 0];
            o.y = empty ? 0.f : acc[i][1] + bias[cbase + c0 + 1];
            o.z = empty ? 0.f : acc[i][2] + bias[cbase + c0 + 2];
            o.w = empty ? 0.f : acc[i][3] + bias[cbase + c0 + 3];
            *(float4*)(out + (size_t)row * 256 + cbase + c0) = o;
        }
    }
}

// ---------------- CSR aggregation (H pre-scaled by dis), 16-deep MLP, fused BN stats ----------------
template <bool STATS>
__global__ __launch_bounds__(256) void k_aggr2(const unsigned short* __restrict__ H,
                                               const int* __restrict__ esrc,
                                               const int* __restrict__ roff,
                                               const float* __restrict__ dis,
                                               const float* __restrict__ bias,
                                               float* __restrict__ out, int N,
                                               float* __restrict__ partial) {
    constexpr int M = 128;
    constexpr int GSZ = 16;
    constexpr int GPB = 16;
    const int nGroups = gridDim.x * GPB;
    const int gid = blockIdx.x * GPB + threadIdx.x / GSZ;
    const int lane = threadIdx.x % GSZ;
    const int c8 = lane * 8;
    const float4 bva = *(const float4*)(bias + c8);
    const float4 bvb = *(const float4*)(bias + c8 + 4);

    float ss[8], sq[8];
    if (STATS) {
#pragma unroll
        for (int k = 0; k < 8; k++) { ss[k] = 0.f; sq[k] = 0.f; }
    }

    for (int n = gid; n < N; n += nGroups) {
        const int rs = roff[n], re = roff[n + 1];
        float acc[8];
#pragma unroll
        for (int j = 0; j < 8; j++) acc[j] = 0.0f;

        int e = rs;
        for (; e + 16 <= re; e += 16) {
            int sid[16];
#pragma unroll
            for (int q = 0; q < 16; q++) sid[q] = esrc[e + q];
            int4 hv[16];
#pragma unroll
            for (int q = 0; q < 16; q++)
                hv[q] = *(const int4*)(H + (size_t)sid[q] * M + c8);
#pragma unroll
            for (int q = 0; q < 16; q++) {
                const int w[4] = {hv[q].x, hv[q].y, hv[q].z, hv[q].w};
#pragma unroll
                for (int k = 0; k < 4; k++) {
                    acc[2 * k + 0] += lo16(w[k]);
                    acc[2 * k + 1] += hi16(w[k]);
                }
            }
        }
        if (e + 8 <= re) {
            int sid[8];
#pragma unroll
            for (int q = 0; q < 8; q++) sid[q] = esrc[e + q];
            int4 hv[8];
#pragma unroll
            for (int q = 0; q < 8; q++)
                hv[q] = *(const int4*)(H + (size_t)sid[q] * M + c8);
#pragma unroll
            for (int q = 0; q < 8; q++) {
                const int w[4] = {hv[q].x, hv[q].y, hv[q].z, hv[q].w};
#pragma unroll
                for (int k = 0; k < 4; k++) {
                    acc[2 * k + 0] += lo16(w[k]);
                    acc[2 * k + 1] += hi16(w[k]);
                }
            }
            e += 8;
        }
        if (e + 4 <= re) {
            int sid[4];
#pragma unroll
            for (int q = 0; q < 4; q++) sid[q] = esrc[e + q];
            int4 hv[4];
#pragma unroll
            for (int q = 0; q < 4; q++)
                hv[q] = *(const int4*)(H + (size_t)sid[q] * M + c8);
#pragma unroll
            for (int q = 0; q < 4; q++) {
                const int w[4] = {hv[q].x, hv[q].y, hv[q].z, hv[q].w};
#pragma unroll
                for (int k = 0; k < 4; k++) {
                    acc[2 * k + 0] += lo16(w[k]);
                    acc[2 * k + 1] += hi16(w[k]);
                }
            }
            e += 4;
        }
        for (; e < re; e++) {
            const int s = esrc[e];
            const int4 h = *(const int4*)(H + (size_t)s * M + c8);
            const int w[4] = {h.x, h.y, h.z, h.w};
#pragma unroll
            for (int k = 0; k < 4; k++) {
                acc[2 * k + 0] += lo16(w[k]);
                acc[2 * k + 1] += hi16(w[k]);
            }
        }
        {
            const int4 h = *(const int4*)(H + (size_t)n * M + c8);
            const int w[4] = {h.x, h.y, h.z, h.w};
#pragma unroll
            for (int k = 0; k < 4; k++) {
                acc[2 * k + 0] += lo16(w[k]);
                acc[2 * k + 1] += hi16(w[k]);
            }
        }
        const float dn = dis[n];
        float ov[8];
#pragma unroll
        for (int k = 0; k < 8; k++) {
            float b = (k < 4) ? (&bva.x)[k] : (&bvb.x)[k - 4];
            ov[k] = acc[k] * dn + b;
            if (STATS) { ss[k] += ov[k]; sq[k] += ov[k] * ov[k]; }
        }
        float4 oa = make_float4(ov[0], ov[1], ov[2], ov[3]);
        float4 ob = make_float4(ov[4], ov[5], ov[6], ov[7]);
        *(float4*)(out + (size_t)n * M + c8) = oa;
        *(float4*)(out + (size_t)n * M + c8 + 4) = ob;
    }

    if (STATS) {
        __shared__ float ls[GPB][256];
        const int g = threadIdx.x / GSZ;
#pragma unroll
        for (int k = 0; k < 8; k++) {
            ls[g][c8 + k] = ss[k];
            ls[g][128 + c8 + k] = sq[k];
        }
        __syncthreads();
        const int f = threadIdx.x;
        float v = 0.f;
#pragma unroll
        for (int gg = 0; gg < GPB; gg++) v += ls[gg][f];
        partial[(size_t)blockIdx.x * 256 + f] = v;
    }
}

// ---------------- reduce partial stats ----------------
__global__ __launch_bounds__(256) void k_redstats(const float* __restrict__ partial,
                                                  float* __restrict__ sums,
                                                  float* __restrict__ sumsq, int nblk) {
    const int f = blockIdx.x;
    const int t = threadIdx.x;
    float v = 0.f;
    for (int b = t; b < nblk; b += 256) v += partial[(size_t)b * 256 + f];
    __shared__ float sh[256];
    sh[t] = v;
    __syncthreads();
    for (int d = 128; d > 0; d >>= 1) {
        if (t < d) sh[t] += sh[t + d];
        __syncthreads();
    }
    if (t == 0) {
        if (f < 128) sums[f] = sh[0];
        else sumsq[f - 128] = sh[0];
    }
}

// ---------------- BN+ReLU -> bf16 cast, pre-scaled by dis ----------------
__global__ void k_bncast(const float* __restrict__ X, const float* __restrict__ sums,
                         const float* __restrict__ sumsq, const float* __restrict__ g,
                         const float* __restrict__ be, const float* __restrict__ dis,
                         unsigned short* __restrict__ Y, long long total4, float inv_n) {
    long long idx = (long long)blockIdx.x * blockDim.x + threadIdx.x;
    if (idx >= total4) return;
    int c4 = ((int)idx & 31) << 2;
    const float dn = dis[(int)(idx >> 5)];
    float4 v = *(const float4*)(X + idx * 4);
    float o[4] = {v.x, v.y, v.z, v.w};
    ushort4 r;
    unsigned short* rp = &r.x;
#pragma unroll
    for (int j = 0; j < 4; j++) {
        int c = c4 + j;
        float mean = sums[c] * inv_n;
        float var = sumsq[c] * inv_n - mean * mean;
        float sc = rsqrtf(var + BN_EPS) * g[c];
        rp[j] = f2bf(fmaxf((o[j] - mean) * sc + be[c], 0.0f) * dn);
    }
    *(ushort4*)(Y + idx * 4) = r;
}

// ---------------- segmented mean pool (batch sorted) ----------------
__global__ void k_pool_seg(const float* __restrict__ H, const int* __restrict__ goff,
                           float* __restrict__ out) {
    const int gr = blockIdx.x;
    const int c = threadIdx.x;  // 128
    const int s = goff[gr], e = goff[gr + 1];
    float acc = 0.0f;
    for (int i = s; i < e; i++) acc += H[(size_t)i * 128 + c];
    out[(size_t)gr * 128 + c] = acc / fmaxf((float)(e - s), 1.0f);
}

extern "C" void kernel_launch(void* const* d_in, const int* in_sizes, int n_in,
                              void* d_out, int out_size, void* d_ws, size_t ws_size,
                              hipStream_t stream) {
    const float* x     = (const float*)d_in[0];
    const int*   ei    = (const int*)d_in[1];
    const int*   batch = (const int*)d_in[2];
    const float* W1 = (const float*)d_in[3];
    const float* b1 = (const float*)d_in[4];
    const float* W2 = (const float*)d_in[5];
    const float* b2 = (const float*)d_in[6];
    const float* W3 = (const float*)d_in[7];
    const float* b3 = (const float*)d_in[8];
    const float* g1 = (const float*)d_in[9];
    const float* be1 = (const float*)d_in[10];
    const float* g2 = (const float*)d_in[11];
    const float* be2 = (const float*)d_in[12];
    float* out = (float*)d_out;

    const int N = in_sizes[2];
    const int E = in_sizes[1] / 2;
    const int G = out_size / 256;
    const int* src = ei;
    const int* tgt = ei + E;

    char* ws = (char*)d_ws;
    auto take = [&](size_t bytes) {
        char* p = ws;
        ws += (bytes + 255) & ~(size_t)255;
        return p;
    };
    float*          bufB   = (float*)take((size_t)N * 128 * 4);
    unsigned short* bufH   = (unsigned short*)take((size_t)N * 128 * 2);
    float*          P      = (float*)take((size_t)G * 128 * 4);
    float*          dis    = (float*)take((size_t)N * 4);
    float*          sums   = (float*)take(512 * 4);
    float*          sumsq  = sums + 128;
    float*          zbias  = (float*)take(128 * 4);
    float*          partial= (float*)take((size_t)AGG_BLOCKS * 256 * 4);
    int*            roff   = (int*)take((size_t)(N + 1) * 4);
    int*            esrc   = (int*)take((size_t)E * 4);
    int*            goff   = (int*)take((size_t)(G + 1) * 4);
    int*            hcnt   = (int*)take((size_t)CB * NBP * 4);
    int*            btot   = (int*)take(NBP * 4);
    int*            bbase  = (int*)take((NBP + 1) * 4);
    int2*           pairs  = (int2*)bufB;  // alias: consumed before bufB's first write

    const int B = 256;
    const int nbuck = cdiv(N, BUCKN);     // <= 256 for N <= 131072
    const int tile = cdiv(E, CB);

    hipMemsetAsync(zbias, 0, 128 * 4, stream);

    // ---- CSR build: bucketed counting sort ----
    k_bhist<<<CB, B, 0, stream>>>(tgt, hcnt, E, tile, nbuck);
    k_bscan<<<nbuck, B, 0, stream>>>(hcnt, btot);
    k_scan_small<<<1, B, 0, stream>>>(btot, bbase, nbuck);
    k_bscatter2<<<CB, B, 0, stream>>>(src, tgt, hcnt, bbase, pairs, E, tile, nbuck);
    k_bucket_csr<<<nbuck, B, 0, stream>>>(pairs, bbase, roff, dis, esrc, N, nbuck);
    k_goff<<<cdiv(N, B), B, 0, stream>>>(batch, goff, N, G);

    long long t4_128 = (long long)N * 32;
    const int nbx = cdiv(N, 64);

    // ---- layer 1 ----
    k_gemm_mfma<false><<<dim3(nbx, 2), B, 0, stream>>>(x, W1, bufH, N, dis,
                                                       nullptr, nullptr, nullptr, nullptr, 0.f);
    k_aggr2<true><<<AGG_BLOCKS, B, 0, stream>>>(bufH, esrc, roff, dis, b1, bufB, N, partial);
    k_redstats<<<256, B, 0, stream>>>(partial, sums, sumsq, AGG_BLOCKS);

    // ---- layer 2 (BN1 fused into MFMA staging) ----
    k_gemm_mfma<true><<<dim3(nbx, 2), B, 0, stream>>>(bufB, W2, bufH, N, dis,
                                                      sums, sumsq, g1, be1, 1.0f / N);
    k_aggr2<true><<<AGG_BLOCKS, B, 0, stream>>>(bufH, esrc, roff, dis, b2, bufB, N, partial);
    k_redstats<<<256, B, 0, stream>>>(partial, sums, sumsq, AGG_BLOCKS);

    // ---- layer 3: BN2+ReLU+dis cast -> aggregate 128-dim -> pool -> small GEMM ----
    k_bncast<<<cdiv(t4_128, B), B, 0, stream>>>(bufB, sums, sumsq, g2, be2, dis, bufH,
                                                t4_128, 1.0f / N);
    k_aggr2<false><<<AGG_BLOCKS, B, 0, stream>>>(bufH, esrc, roff, dis, zbias, bufB, N, nullptr);
    k_pool_seg<<<G, 128, 0, stream>>>(bufB, goff, P);
    k_gemm_final<<<dim3(cdiv(G, 64), 4), B, 0, stream>>>(P, W3, b3, goff, out, G);
}

// Round 11
// 361.478 us; speedup vs baseline: 2.3081x; 1.0717x over previous
//
#include <hip/hip_runtime.h>
#include <hip/hip_bf16.h>

#define BN_EPS 1e-5f
#define AGG_BLOCKS 2048
#define BSHIFT 9         // bucket = tgt >> 9 (512 nodes/bucket)
#define BUCKN 512
#define NBP 256          // padded buckets per hcnt row (requires nbuck <= 256)
#define CB 256           // scatter blocks

static inline int cdiv(long long a, long long b) { return (int)((a + b - 1) / b); }

typedef __attribute__((ext_vector_type(8))) short short8v;
typedef __attribute__((ext_vector_type(4))) float f32x4;

__device__ __forceinline__ float lo16(int u) {
    return __uint_as_float(((unsigned int)u) << 16);
}
__device__ __forceinline__ float hi16(int u) {
    return __uint_as_float(((unsigned int)u) & 0xffff0000u);
}
__device__ __forceinline__ unsigned short f2bf(float f) {
    unsigned int b = __float_as_uint(f);
    b += 0x7FFFu + ((b >> 16) & 1u);  // RNE
    return (unsigned short)(b >> 16);
}

// ---------------- pass A: per-block bucket histogram (LDS) ----------------
__global__ __launch_bounds__(256) void k_bhist(const int* __restrict__ tgt,
                                               int* __restrict__ hcnt, int E, int tile,
                                               int nbuck) {
    __shared__ int lh[NBP];
    const int t = threadIdx.x;
    lh[t] = 0;
    __syncthreads();
    const int base = blockIdx.x * tile;
    const int end = min(base + tile, E);
    for (int i = base + t; i < end; i += 256)
        atomicAdd(&lh[tgt[i] >> BSHIFT], 1);
    __syncthreads();
    if (t < nbuck) hcnt[blockIdx.x * NBP + t] = lh[t];
}

// ---------------- B1: per-bucket exclusive scan across blocks ----------------
__global__ __launch_bounds__(256) void k_bscan(int* __restrict__ hcnt,
                                               int* __restrict__ btot) {
    const int bucket = blockIdx.x;
    const int t = threadIdx.x;
    __shared__ int sh[256];
    int v = hcnt[t * NBP + bucket];
    sh[t] = v;
    __syncthreads();
    for (int d = 1; d < 256; d <<= 1) {
        int u = (t >= d) ? sh[t - d] : 0;
        __syncthreads();
        sh[t] += u;
        __syncthreads();
    }
    hcnt[t * NBP + bucket] = sh[t] - v;
    if (t == 255) btot[bucket] = sh[255];
}

// ---------------- B2: scan of bucket totals -> bbase[nbuck+1] ----------------
__global__ __launch_bounds__(256) void k_scan_small(const int* __restrict__ btot,
                                                    int* __restrict__ bbase, int nb) {
    const int t = threadIdx.x;
    __shared__ int sh[256];
    int v = (t < nb) ? btot[t] : 0;
    sh[t] = v;
    __syncthreads();
    for (int d = 1; d < 256; d <<= 1) {
        int u = (t >= d) ? sh[t - d] : 0;
        __syncthreads();
        sh[t] += u;
        __syncthreads();
    }
    if (t < nb) bbase[t] = sh[t] - v;
    if (t == nb) bbase[nb] = sh[255];
    if (t == 255 && nb <= 255) bbase[nb] = sh[255];
}

// ---------------- pass C: scatter pairs into bucket-grouped order ----------------
__global__ __launch_bounds__(256) void k_bscatter2(const int* __restrict__ src,
                                                   const int* __restrict__ tgt,
                                                   const int* __restrict__ hcnt,
                                                   const int* __restrict__ bbase,
                                                   int2* __restrict__ pairs, int E,
                                                   int tile, int nbuck) {
    __shared__ int cur[NBP];
    const int t = threadIdx.x;
    if (t < nbuck) cur[t] = bbase[t] + hcnt[blockIdx.x * NBP + t];
    __syncthreads();
    const int base = blockIdx.x * tile;
    const int end = min(base + tile, E);
    for (int i = base + t; i < end; i += 256) {
        int s = src[i];
        int tg = tgt[i];
        int p = atomicAdd(&cur[tg >> BSHIFT], 1);
        pairs[p] = make_int2(s, tg);
    }
}

// ---------------- pass D: per-bucket CSR finish + goff (fused as extra blocks) ----------------
__global__ __launch_bounds__(256) void k_bucket_csr(const int2* __restrict__ pairs,
                                                    const int* __restrict__ bbase,
                                                    int* __restrict__ roff,
                                                    float* __restrict__ dis,
                                                    int* __restrict__ esrc,
                                                    int N, int nbuck,
                                                    const int* __restrict__ batch,
                                                    int* __restrict__ goff, int G) {
    const int t = threadIdx.x;
    if ((int)blockIdx.x >= nbuck) {
        // ---- goff path: boundaries of sorted batch ----
        int i = (blockIdx.x - nbuck) * 256 + t;
        if (i >= N) return;
        int cur = batch[i];
        int prev = (i == 0) ? -1 : batch[i - 1];
        for (int g = prev + 1; g <= cur; g++) goff[g] = i;
        if (i == N - 1) {
            for (int g = cur + 1; g <= G; g++) goff[g] = N;
        }
        return;
    }
    __shared__ int cnt[BUCKN];
    __shared__ int cur[BUCKN];
    __shared__ int sh[256];
    const int b = blockIdx.x;
    const int nb0 = b * BUCKN;
    cnt[t] = 0;
    cnt[t + 256] = 0;
    __syncthreads();
    const int lo = bbase[b], hi = bbase[b + 1];
    for (int p = lo + t; p < hi; p += 256)
        atomicAdd(&cnt[pairs[p].y - nb0], 1);
    __syncthreads();
    const int c0 = cnt[2 * t], c1 = cnt[2 * t + 1];
    int s = c0 + c1;
    sh[t] = s;
    __syncthreads();
    for (int d = 1; d < 256; d <<= 1) {
        int u = (t >= d) ? sh[t - d] : 0;
        __syncthreads();
        sh[t] += u;
        __syncthreads();
    }
    const int excl = sh[t] - s + lo;  // absolute offset of node nb0+2t
    cur[2 * t] = excl;
    cur[2 * t + 1] = excl + c0;
    const int n0 = nb0 + 2 * t, n1 = n0 + 1;
    if (n0 < N) { roff[n0] = excl; dis[n0] = rsqrtf((float)c0 + 1.0f); }
    if (n1 < N) { roff[n1] = excl + c0; dis[n1] = rsqrtf((float)c1 + 1.0f); }
    if (b == nbuck - 1 && t == 0) roff[N] = hi;
    __syncthreads();
    for (int p = lo + t; p < hi; p += 256) {
        int2 e = pairs[p];
        int q = atomicAdd(&cur[e.y - nb0], 1);
        esrc[q] = e.x;
    }
}

// ---------------- MFMA GEMM: Ybf16[N,128] = (BN?(X) @ W[128,128]) * dis[row] ----------------
template <bool BN>
__global__ __launch_bounds__(256) void k_gemm_mfma(const float* __restrict__ X,
                                                   const float* __restrict__ W,
                                                   unsigned short* __restrict__ Y, int N,
                                                   const float* __restrict__ dis,
                                                   const float* __restrict__ sums,
                                                   const float* __restrict__ sumsq,
                                                   const float* __restrict__ g,
                                                   const float* __restrict__ be,
                                                   float inv_n) {
    __shared__ unsigned short As[64][136];
    __shared__ unsigned short Bs[64][136];
    const int t = threadIdx.x;
    const int rbase = blockIdx.x * 64;
    const int cbase = blockIdx.y * 64;

    for (int it = 0; it < 8; it++) {
        int idx = t + it * 256;
        int r = idx >> 5;
        int k4 = (idx & 31) * 4;
        int row = rbase + r;
        float4 v = make_float4(0.f, 0.f, 0.f, 0.f);
        if (row < N) v = *(const float4*)(X + (size_t)row * 128 + k4);
        float o[4] = {v.x, v.y, v.z, v.w};
        if (BN) {
#pragma unroll
            for (int j = 0; j < 4; j++) {
                int c = k4 + j;
                float mean = sums[c] * inv_n;
                float var = sumsq[c] * inv_n - mean * mean;
                float sc = rsqrtf(var + BN_EPS) * g[c];
                o[j] = fmaxf((o[j] - mean) * sc + be[c], 0.0f);
            }
        }
        ushort4 u;
        u.x = f2bf(o[0]); u.y = f2bf(o[1]); u.z = f2bf(o[2]); u.w = f2bf(o[3]);
        *(ushort4*)&As[r][k4] = u;
    }
    for (int it = 0; it < 8; it++) {
        int idx = t + it * 256;
        int k = idx >> 4;
        int c4 = (idx & 15) * 4;
        float4 v = *(const float4*)(W + (size_t)k * 128 + cbase + c4);
        Bs[c4 + 0][k] = f2bf(v.x);
        Bs[c4 + 1][k] = f2bf(v.y);
        Bs[c4 + 2][k] = f2bf(v.z);
        Bs[c4 + 3][k] = f2bf(v.w);
    }
    __syncthreads();

    const int wid = t >> 6;
    const int lane = t & 63;
    const int wr = (wid >> 1) * 32;
    const int wc = (wid & 1) * 32;
    const int lrow = lane & 15;
    const int lkg = lane >> 4;

    f32x4 acc00 = 0, acc01 = 0, acc10 = 0, acc11 = 0;
#pragma unroll
    for (int kk = 0; kk < 4; kk++) {
        const int k0 = kk * 32 + lkg * 8;
        short8v a0 = *(const short8v*)&As[wr + lrow][k0];
        short8v a1 = *(const short8v*)&As[wr + 16 + lrow][k0];
        short8v b0 = *(const short8v*)&Bs[wc + lrow][k0];
        short8v b1 = *(const short8v*)&Bs[wc + 16 + lrow][k0];
        acc00 = __builtin_amdgcn_mfma_f32_16x16x32_bf16(a0, b0, acc00, 0, 0, 0);
        acc01 = __builtin_amdgcn_mfma_f32_16x16x32_bf16(a0, b1, acc01, 0, 0, 0);
        acc10 = __builtin_amdgcn_mfma_f32_16x16x32_bf16(a1, b0, acc10, 0, 0, 0);
        acc11 = __builtin_amdgcn_mfma_f32_16x16x32_bf16(a1, b1, acc11, 0, 0, 0);
    }

#pragma unroll
    for (int rt = 0; rt < 2; rt++) {
        const f32x4 va = rt ? acc10 : acc00;
        const f32x4 vb = rt ? acc11 : acc01;
#pragma unroll
        for (int reg = 0; reg < 4; reg++) {
            int row = rbase + wr + rt * 16 + lkg * 4 + reg;
            if (row < N) {
                float dv = dis[row];
                Y[(size_t)row * 128 + cbase + wc + lrow] = f2bf(va[reg] * dv);
                Y[(size_t)row * 128 + cbase + wc + 16 + lrow] = f2bf(vb[reg] * dv);
            }
        }
    }
}

// ---------------- final GEMM: out[G,256] = P[G,128] @ W3 + b3 (empty-graph guard) ----------------
__global__ __launch_bounds__(256) void k_gemm_final(const float* __restrict__ X,
                                                    const float* __restrict__ W,
                                                    const float* __restrict__ bias,
                                                    const int* __restrict__ goff,
                                                    float* __restrict__ out, int G) {
    __shared__ float xt[128][64];
    __shared__ float wt[128][64];
    const int t = threadIdx.x;
    const int rbase = blockIdx.x * 64;
    const int cbase = blockIdx.y * 64;

    for (int it = 0; it < 8; it++) {
        int idx = t + it * 256;
        int k4 = idx >> 6;
        int r = idx & 63;
        int row = rbase + r;
        float4 v = make_float4(0.f, 0.f, 0.f, 0.f);
        if (row < G) v = *(const float4*)(X + (size_t)row * 128 + k4 * 4);
        xt[k4 * 4 + 0][r] = v.x;
        xt[k4 * 4 + 1][r] = v.y;
        xt[k4 * 4 + 2][r] = v.z;
        xt[k4 * 4 + 3][r] = v.w;
    }
    for (int it = 0; it < 8; it++) {
        int idx = t + it * 256;
        int k = idx >> 4;
        int c4 = (idx & 15) * 4;
        *(float4*)&wt[k][c4] = *(const float4*)(W + (size_t)k * 256 + cbase + c4);
    }
    __syncthreads();

    const int r0 = (t >> 4) * 4;
    const int c0 = (t & 15) * 4;
    float acc[4][4];
#pragma unroll
    for (int i = 0; i < 4; i++)
#pragma unroll
        for (int j = 0; j < 4; j++) acc[i][j] = 0.0f;

#pragma unroll 4
    for (int k = 0; k < 128; k++) {
        float4 a = *(const float4*)&xt[k][r0];
        float4 b = *(const float4*)&wt[k][c0];
        const float av[4] = {a.x, a.y, a.z, a.w};
        const float bv[4] = {b.x, b.y, b.z, b.w};
#pragma unroll
        for (int i = 0; i < 4; i++)
#pragma unroll
            for (int j = 0; j < 4; j++) acc[i][j] += av[i] * bv[j];
    }

#pragma unroll
    for (int i = 0; i < 4; i++) {
        int row = rbase + r0 + i;
        if (row < G) {
            bool empty = (goff[row + 1] == goff[row]);
            float4 o;
            o.x = empty ? 0.f : acc[i][0] + bias[cbase + c0 + 0];
            o.y = empty ? 0.f : acc[i][1] + bias[cbase + c0 + 1];
            o.z = empty ? 0.f : acc[i][2] + bias[cbase + c0 + 2];
            o.w = empty ? 0.f : acc[i][3] + bias[cbase + c0 + 3];
            *(float4*)(out + (size_t)row * 256 + cbase + c0) = o;
        }
    }
}

// ---------------- CSR aggregation (H pre-scaled by dis), 8-deep MLP, fused BN stats ----------------
// bias == nullptr -> zero bias
template <bool STATS>
__global__ __launch_bounds__(256) void k_aggr2(const unsigned short* __restrict__ H,
                                               const int* __restrict__ esrc,
                                               const int* __restrict__ roff,
                                               const float* __restrict__ dis,
                                               const float* __restrict__ bias,
                                               float* __restrict__ out, int N,
                                               float* __restrict__ partial) {
    constexpr int M = 128;
    constexpr int GSZ = 16;
    constexpr int GPB = 16;
    const int nGroups = gridDim.x * GPB;
    const int gid = blockIdx.x * GPB + threadIdx.x / GSZ;
    const int lane = threadIdx.x % GSZ;
    const int c8 = lane * 8;
    float4 bva = make_float4(0.f, 0.f, 0.f, 0.f);
    float4 bvb = make_float4(0.f, 0.f, 0.f, 0.f);
    if (bias) {
        bva = *(const float4*)(bias + c8);
        bvb = *(const float4*)(bias + c8 + 4);
    }

    float ss[8], sq[8];
    if (STATS) {
#pragma unroll
        for (int k = 0; k < 8; k++) { ss[k] = 0.f; sq[k] = 0.f; }
    }

    for (int n = gid; n < N; n += nGroups) {
        const int rs = roff[n], re = roff[n + 1];
        float acc[8];
#pragma unroll
        for (int j = 0; j < 8; j++) acc[j] = 0.0f;

        int e = rs;
        for (; e + 8 <= re; e += 8) {
            int sid[8];
#pragma unroll
            for (int q = 0; q < 8; q++) sid[q] = esrc[e + q];
            int4 hv[8];
#pragma unroll
            for (int q = 0; q < 8; q++)
                hv[q] = *(const int4*)(H + (size_t)sid[q] * M + c8);
#pragma unroll
            for (int q = 0; q < 8; q++) {
                const int w[4] = {hv[q].x, hv[q].y, hv[q].z, hv[q].w};
#pragma unroll
                for (int k = 0; k < 4; k++) {
                    acc[2 * k + 0] += lo16(w[k]);
                    acc[2 * k + 1] += hi16(w[k]);
                }
            }
        }
        if (e + 4 <= re) {
            int sid[4];
#pragma unroll
            for (int q = 0; q < 4; q++) sid[q] = esrc[e + q];
            int4 hv[4];
#pragma unroll
            for (int q = 0; q < 4; q++)
                hv[q] = *(const int4*)(H + (size_t)sid[q] * M + c8);
#pragma unroll
            for (int q = 0; q < 4; q++) {
                const int w[4] = {hv[q].x, hv[q].y, hv[q].z, hv[q].w};
#pragma unroll
                for (int k = 0; k < 4; k++) {
                    acc[2 * k + 0] += lo16(w[k]);
                    acc[2 * k + 1] += hi16(w[k]);
                }
            }
            e += 4;
        }
        for (; e < re; e++) {
            const int s = esrc[e];
            const int4 h = *(const int4*)(H + (size_t)s * M + c8);
            const int w[4] = {h.x, h.y, h.z, h.w};
#pragma unroll
            for (int k = 0; k < 4; k++) {
                acc[2 * k + 0] += lo16(w[k]);
                acc[2 * k + 1] += hi16(w[k]);
            }
        }
        {
            const int4 h = *(const int4*)(H + (size_t)n * M + c8);
            const int w[4] = {h.x, h.y, h.z, h.w};
#pragma unroll
            for (int k = 0; k < 4; k++) {
                acc[2 * k + 0] += lo16(w[k]);
                acc[2 * k + 1] += hi16(w[k]);
            }
        }
        const float dn = dis[n];
        float ov[8];
#pragma unroll
        for (int k = 0; k < 8; k++) {
            float b = (k < 4) ? (&bva.x)[k] : (&bvb.x)[k - 4];
            ov[k] = acc[k] * dn + b;
            if (STATS) { ss[k] += ov[k]; sq[k] += ov[k] * ov[k]; }
        }
        float4 oa = make_float4(ov[0], ov[1], ov[2], ov[3]);
        float4 ob = make_float4(ov[4], ov[5], ov[6], ov[7]);
        *(float4*)(out + (size_t)n * M + c8) = oa;
        *(float4*)(out + (size_t)n * M + c8 + 4) = ob;
    }

    if (STATS) {
        __shared__ float ls[GPB][256];
        const int g = threadIdx.x / GSZ;
#pragma unroll
        for (int k = 0; k < 8; k++) {
            ls[g][c8 + k] = ss[k];
            ls[g][128 + c8 + k] = sq[k];
        }
        __syncthreads();
        const int f = threadIdx.x;
        float v = 0.f;
#pragma unroll
        for (int gg = 0; gg < GPB; gg++) v += ls[gg][f];
        partial[(size_t)blockIdx.x * 256 + f] = v;
    }
}

// ---------------- reduce partial stats ----------------
__global__ __launch_bounds__(256) void k_redstats(const float* __restrict__ partial,
                                                  float* __restrict__ sums,
                                                  float* __restrict__ sumsq, int nblk) {
    const int f = blockIdx.x;
    const int t = threadIdx.x;
    float v = 0.f;
    for (int b = t; b < nblk; b += 256) v += partial[(size_t)b * 256 + f];
    __shared__ float sh[256];
    sh[t] = v;
    __syncthreads();
    for (int d = 128; d > 0; d >>= 1) {
        if (t < d) sh[t] += sh[t + d];
        __syncthreads();
    }
    if (t == 0) {
        if (f < 128) sums[f] = sh[0];
        else sumsq[f - 128] = sh[0];
    }
}

// ---------------- BN+ReLU -> bf16 cast, pre-scaled by dis ----------------
__global__ void k_bncast(const float* __restrict__ X, const float* __restrict__ sums,
                         const float* __restrict__ sumsq, const float* __restrict__ g,
                         const float* __restrict__ be, const float* __restrict__ dis,
                         unsigned short* __restrict__ Y, long long total4, float inv_n) {
    long long idx = (long long)blockIdx.x * blockDim.x + threadIdx.x;
    if (idx >= total4) return;
    int c4 = ((int)idx & 31) << 2;
    const float dn = dis[(int)(idx >> 5)];
    float4 v = *(const float4*)(X + idx * 4);
    float o[4] = {v.x, v.y, v.z, v.w};
    ushort4 r;
    unsigned short* rp = &r.x;
#pragma unroll
    for (int j = 0; j < 4; j++) {
        int c = c4 + j;
        float mean = sums[c] * inv_n;
        float var = sumsq[c] * inv_n - mean * mean;
        float sc = rsqrtf(var + BN_EPS) * g[c];
        rp[j] = f2bf(fmaxf((o[j] - mean) * sc + be[c], 0.0f) * dn);
    }
    *(ushort4*)(Y + idx * 4) = r;
}

// ---------------- segmented mean pool (batch sorted) ----------------
__global__ void k_pool_seg(const float* __restrict__ H, const int* __restrict__ goff,
                           float* __restrict__ out) {
    const int gr = blockIdx.x;
    const int c = threadIdx.x;  // 128
    const int s = goff[gr], e = goff[gr + 1];
    float acc = 0.0f;
    for (int i = s; i < e; i++) acc += H[(size_t)i * 128 + c];
    out[(size_t)gr * 128 + c] = acc / fmaxf((float)(e - s), 1.0f);
}

extern "C" void kernel_launch(void* const* d_in, const int* in_sizes, int n_in,
                              void* d_out, int out_size, void* d_ws, size_t ws_size,
                              hipStream_t stream) {
    const float* x     = (const float*)d_in[0];
    const int*   ei    = (const int*)d_in[1];
    const int*   batch = (const int*)d_in[2];
    const float* W1 = (const float*)d_in[3];
    const float* b1 = (const float*)d_in[4];
    const float* W2 = (const float*)d_in[5];
    const float* b2 = (const float*)d_in[6];
    const float* W3 = (const float*)d_in[7];
    const float* b3 = (const float*)d_in[8];
    const float* g1 = (const float*)d_in[9];
    const float* be1 = (const float*)d_in[10];
    const float* g2 = (const float*)d_in[11];
    const float* be2 = (const float*)d_in[12];
    float* out = (float*)d_out;

    const int N = in_sizes[2];
    const int E = in_sizes[1] / 2;
    const int G = out_size / 256;
    const int* src = ei;
    const int* tgt = ei + E;

    char* ws = (char*)d_ws;
    auto take = [&](size_t bytes) {
        char* p = ws;
        ws += (bytes + 255) & ~(size_t)255;
        return p;
    };
    float*          bufB   = (float*)take((size_t)N * 128 * 4);
    unsigned short* bufH   = (unsigned short*)take((size_t)N * 128 * 2);
    float*          P      = (float*)take((size_t)G * 128 * 4);
    float*          dis    = (float*)take((size_t)N * 4);
    float*          sums   = (float*)take(512 * 4);
    float*          sumsq  = sums + 128;
    float*          partial= (float*)take((size_t)AGG_BLOCKS * 256 * 4);
    int*            roff   = (int*)take((size_t)(N + 1) * 4);
    int*            esrc   = (int*)take((size_t)E * 4);
    int*            goff   = (int*)take((size_t)(G + 1) * 4);
    int*            hcnt   = (int*)take((size_t)CB * NBP * 4);
    int*            btot   = (int*)take(NBP * 4);
    int*            bbase  = (int*)take((NBP + 1) * 4);
    int2*           pairs  = (int2*)bufB;  // alias: consumed before bufB's first write

    const int B = 256;
    const int nbuck = cdiv(N, BUCKN);     // <= 256 for N <= 131072
    const int tile = cdiv(E, CB);

    // ---- CSR build: bucketed counting sort ----
    k_bhist<<<CB, B, 0, stream>>>(tgt, hcnt, E, tile, nbuck);
    k_bscan<<<nbuck, B, 0, stream>>>(hcnt, btot);
    k_scan_small<<<1, B, 0, stream>>>(btot, bbase, nbuck);
    k_bscatter2<<<CB, B, 0, stream>>>(src, tgt, hcnt, bbase, pairs, E, tile, nbuck);
    k_bucket_csr<<<nbuck + cdiv(N, B), B, 0, stream>>>(pairs, bbase, roff, dis, esrc,
                                                       N, nbuck, batch, goff, G);

    long long t4_128 = (long long)N * 32;
    const int nbx = cdiv(N, 64);

    // ---- layer 1 ----
    k_gemm_mfma<false><<<dim3(nbx, 2), B, 0, stream>>>(x, W1, bufH, N, dis,
                                                       nullptr, nullptr, nullptr, nullptr, 0.f);
    k_aggr2<true><<<AGG_BLOCKS, B, 0, stream>>>(bufH, esrc, roff, dis, b1, bufB, N, partial);
    k_redstats<<<256, B, 0, stream>>>(partial, sums, sumsq, AGG_BLOCKS);

    // ---- layer 2 (BN1 fused into MFMA staging) ----
    k_gemm_mfma<true><<<dim3(nbx, 2), B, 0, stream>>>(bufB, W2, bufH, N, dis,
                                                      sums, sumsq, g1, be1, 1.0f / N);
    k_aggr2<true><<<AGG_BLOCKS, B, 0, stream>>>(bufH, esrc, roff, dis, b2, bufB, N, partial);
    k_redstats<<<256, B, 0, stream>>>(partial, sums, sumsq, AGG_BLOCKS);

    // ---- layer 3: BN2+ReLU+dis cast -> aggregate 128-dim -> pool -> small GEMM ----
    k_bncast<<<cdiv(t4_128, B), B, 0, stream>>>(bufB, sums, sumsq, g2, be2, dis, bufH,
                                                t4_128, 1.0f / N);
    k_aggr2<false><<<AGG_BLOCKS, B, 0, stream>>>(bufH, esrc, roff, dis, nullptr, bufB, N, nullptr);
    k_pool_seg<<<G, 128, 0, stream>>>(bufB, goff, P);
    k_gemm_final<<<dim3(cdiv(G, 64), 4), B, 0, stream>>>(P, W3, b3, goff, out, G);
}

// Round 12
// 340.643 us; speedup vs baseline: 2.4493x; 1.0612x over previous
//
#include <hip/hip_runtime.h>
#include <hip/hip_bf16.h>

#define BN_EPS 1e-5f
#define AGG_BLOCKS 2048
#define BSHIFT 9         // bucket = tgt >> 9 (512 nodes/bucket)
#define BUCKN 512
#define NBP 256          // padded buckets per hcnt row (requires nbuck <= 256)
#define CB 256           // scatter blocks

static inline int cdiv(long long a, long long b) { return (int)((a + b - 1) / b); }

typedef __attribute__((ext_vector_type(8))) short short8v;
typedef __attribute__((ext_vector_type(4))) float f32x4;

__device__ __forceinline__ float bf2f(unsigned short u) {
    return __uint_as_float(((unsigned int)u) << 16);
}
__device__ __forceinline__ float lo16(int u) {
    return __uint_as_float(((unsigned int)u) << 16);
}
__device__ __forceinline__ float hi16(int u) {
    return __uint_as_float(((unsigned int)u) & 0xffff0000u);
}
__device__ __forceinline__ unsigned short f2bf(float f) {
    unsigned int b = __float_as_uint(f);
    b += 0x7FFFu + ((b >> 16) & 1u);  // RNE
    return (unsigned short)(b >> 16);
}
__device__ __forceinline__ int pack2bf(float a, float b) {
    return (int)f2bf(a) | ((int)f2bf(b) << 16);
}

// ---------------- pass A: per-block bucket histogram (LDS) ----------------
__global__ __launch_bounds__(256) void k_bhist(const int* __restrict__ tgt,
                                               int* __restrict__ hcnt, int E, int tile,
                                               int nbuck) {
    __shared__ int lh[NBP];
    const int t = threadIdx.x;
    lh[t] = 0;
    __syncthreads();
    const int base = blockIdx.x * tile;
    const int end = min(base + tile, E);
    for (int i = base + t; i < end; i += 256)
        atomicAdd(&lh[tgt[i] >> BSHIFT], 1);
    __syncthreads();
    if (t < nbuck) hcnt[blockIdx.x * NBP + t] = lh[t];
}

// ---------------- B1: per-bucket exclusive scan across blocks ----------------
__global__ __launch_bounds__(256) void k_bscan(int* __restrict__ hcnt,
                                               int* __restrict__ btot) {
    const int bucket = blockIdx.x;
    const int t = threadIdx.x;
    __shared__ int sh[256];
    int v = hcnt[t * NBP + bucket];
    sh[t] = v;
    __syncthreads();
    for (int d = 1; d < 256; d <<= 1) {
        int u = (t >= d) ? sh[t - d] : 0;
        __syncthreads();
        sh[t] += u;
        __syncthreads();
    }
    hcnt[t * NBP + bucket] = sh[t] - v;
    if (t == 255) btot[bucket] = sh[255];
}

// ---------------- B2: scan of bucket totals -> bbase[nbuck+1] ----------------
__global__ __launch_bounds__(256) void k_scan_small(const int* __restrict__ btot,
                                                    int* __restrict__ bbase, int nb) {
    const int t = threadIdx.x;
    __shared__ int sh[256];
    int v = (t < nb) ? btot[t] : 0;
    sh[t] = v;
    __syncthreads();
    for (int d = 1; d < 256; d <<= 1) {
        int u = (t >= d) ? sh[t - d] : 0;
        __syncthreads();
        sh[t] += u;
        __syncthreads();
    }
    if (t < nb) bbase[t] = sh[t] - v;
    if (t == nb) bbase[nb] = sh[255];
    if (t == 255 && nb <= 255) bbase[nb] = sh[255];
}

// ---------------- pass C: scatter pairs into bucket-grouped order ----------------
__global__ __launch_bounds__(256) void k_bscatter2(const int* __restrict__ src,
                                                   const int* __restrict__ tgt,
                                                   const int* __restrict__ hcnt,
                                                   const int* __restrict__ bbase,
                                                   int2* __restrict__ pairs, int E,
                                                   int tile, int nbuck) {
    __shared__ int cur[NBP];
    const int t = threadIdx.x;
    if (t < nbuck) cur[t] = bbase[t] + hcnt[blockIdx.x * NBP + t];
    __syncthreads();
    const int base = blockIdx.x * tile;
    const int end = min(base + tile, E);
    for (int i = base + t; i < end; i += 256) {
        int s = src[i];
        int tg = tgt[i];
        int p = atomicAdd(&cur[tg >> BSHIFT], 1);
        pairs[p] = make_int2(s, tg);
    }
}

// ---------------- pass D: per-bucket CSR finish + goff (fused as extra blocks) ----------------
__global__ __launch_bounds__(256) void k_bucket_csr(const int2* __restrict__ pairs,
                                                    const int* __restrict__ bbase,
                                                    int* __restrict__ roff,
                                                    float* __restrict__ dis,
                                                    int* __restrict__ esrc,
                                                    int N, int nbuck,
                                                    const int* __restrict__ batch,
                                                    int* __restrict__ goff, int G) {
    const int t = threadIdx.x;
    if ((int)blockIdx.x >= nbuck) {
        int i = (blockIdx.x - nbuck) * 256 + t;
        if (i >= N) return;
        int cur = batch[i];
        int prev = (i == 0) ? -1 : batch[i - 1];
        for (int g = prev + 1; g <= cur; g++) goff[g] = i;
        if (i == N - 1) {
            for (int g = cur + 1; g <= G; g++) goff[g] = N;
        }
        return;
    }
    __shared__ int cnt[BUCKN];
    __shared__ int cur[BUCKN];
    __shared__ int sh[256];
    const int b = blockIdx.x;
    const int nb0 = b * BUCKN;
    cnt[t] = 0;
    cnt[t + 256] = 0;
    __syncthreads();
    const int lo = bbase[b], hi = bbase[b + 1];
    for (int p = lo + t; p < hi; p += 256)
        atomicAdd(&cnt[pairs[p].y - nb0], 1);
    __syncthreads();
    const int c0 = cnt[2 * t], c1 = cnt[2 * t + 1];
    int s = c0 + c1;
    sh[t] = s;
    __syncthreads();
    for (int d = 1; d < 256; d <<= 1) {
        int u = (t >= d) ? sh[t - d] : 0;
        __syncthreads();
        sh[t] += u;
        __syncthreads();
    }
    const int excl = sh[t] - s + lo;
    cur[2 * t] = excl;
    cur[2 * t + 1] = excl + c0;
    const int n0 = nb0 + 2 * t, n1 = n0 + 1;
    if (n0 < N) { roff[n0] = excl; dis[n0] = rsqrtf((float)c0 + 1.0f); }
    if (n1 < N) { roff[n1] = excl + c0; dis[n1] = rsqrtf((float)c1 + 1.0f); }
    if (b == nbuck - 1 && t == 0) roff[N] = hi;
    __syncthreads();
    for (int p = lo + t; p < hi; p += 256) {
        int2 e = pairs[p];
        int q = atomicAdd(&cur[e.y - nb0], 1);
        esrc[q] = e.x;
    }
}

// ---------------- MFMA GEMM: Ybf16[N,128] = (BN?(X) @ W[128,128]) * dis[row] ----------------
// BN=false: X is f32 ; BN=true: X is bf16 (aggregation output)
template <bool BN>
__global__ __launch_bounds__(256) void k_gemm_mfma(const void* __restrict__ Xv,
                                                   const float* __restrict__ W,
                                                   unsigned short* __restrict__ Y, int N,
                                                   const float* __restrict__ dis,
                                                   const float* __restrict__ sums,
                                                   const float* __restrict__ sumsq,
                                                   const float* __restrict__ g,
                                                   const float* __restrict__ be,
                                                   float inv_n) {
    __shared__ unsigned short As[64][136];
    __shared__ unsigned short Bs[64][136];
    const int t = threadIdx.x;
    const int rbase = blockIdx.x * 64;
    const int cbase = blockIdx.y * 64;

    for (int it = 0; it < 8; it++) {
        int idx = t + it * 256;
        int r = idx >> 5;
        int k4 = (idx & 31) * 4;
        int row = rbase + r;
        float o[4] = {0.f, 0.f, 0.f, 0.f};
        if (row < N) {
            if constexpr (BN) {
                const unsigned short* Xb = (const unsigned short*)Xv;
                ushort4 uv = *(const ushort4*)(Xb + (size_t)row * 128 + k4);
                o[0] = bf2f(uv.x); o[1] = bf2f(uv.y); o[2] = bf2f(uv.z); o[3] = bf2f(uv.w);
            } else {
                const float* Xf = (const float*)Xv;
                float4 v = *(const float4*)(Xf + (size_t)row * 128 + k4);
                o[0] = v.x; o[1] = v.y; o[2] = v.z; o[3] = v.w;
            }
        }
        if (BN) {
#pragma unroll
            for (int j = 0; j < 4; j++) {
                int c = k4 + j;
                float mean = sums[c] * inv_n;
                float var = sumsq[c] * inv_n - mean * mean;
                float sc = rsqrtf(var + BN_EPS) * g[c];
                o[j] = fmaxf((o[j] - mean) * sc + be[c], 0.0f);
            }
        }
        ushort4 u;
        u.x = f2bf(o[0]); u.y = f2bf(o[1]); u.z = f2bf(o[2]); u.w = f2bf(o[3]);
        *(ushort4*)&As[r][k4] = u;
    }
    for (int it = 0; it < 8; it++) {
        int idx = t + it * 256;
        int k = idx >> 4;
        int c4 = (idx & 15) * 4;
        float4 v = *(const float4*)(W + (size_t)k * 128 + cbase + c4);
        Bs[c4 + 0][k] = f2bf(v.x);
        Bs[c4 + 1][k] = f2bf(v.y);
        Bs[c4 + 2][k] = f2bf(v.z);
        Bs[c4 + 3][k] = f2bf(v.w);
    }
    __syncthreads();

    const int wid = t >> 6;
    const int lane = t & 63;
    const int wr = (wid >> 1) * 32;
    const int wc = (wid & 1) * 32;
    const int lrow = lane & 15;
    const int lkg = lane >> 4;

    f32x4 acc00 = 0, acc01 = 0, acc10 = 0, acc11 = 0;
#pragma unroll
    for (int kk = 0; kk < 4; kk++) {
        const int k0 = kk * 32 + lkg * 8;
        short8v a0 = *(const short8v*)&As[wr + lrow][k0];
        short8v a1 = *(const short8v*)&As[wr + 16 + lrow][k0];
        short8v b0 = *(const short8v*)&Bs[wc + lrow][k0];
        short8v b1 = *(const short8v*)&Bs[wc + 16 + lrow][k0];
        acc00 = __builtin_amdgcn_mfma_f32_16x16x32_bf16(a0, b0, acc00, 0, 0, 0);
        acc01 = __builtin_amdgcn_mfma_f32_16x16x32_bf16(a0, b1, acc01, 0, 0, 0);
        acc10 = __builtin_amdgcn_mfma_f32_16x16x32_bf16(a1, b0, acc10, 0, 0, 0);
        acc11 = __builtin_amdgcn_mfma_f32_16x16x32_bf16(a1, b1, acc11, 0, 0, 0);
    }

#pragma unroll
    for (int rt = 0; rt < 2; rt++) {
        const f32x4 va = rt ? acc10 : acc00;
        const f32x4 vb = rt ? acc11 : acc01;
#pragma unroll
        for (int reg = 0; reg < 4; reg++) {
            int row = rbase + wr + rt * 16 + lkg * 4 + reg;
            if (row < N) {
                float dv = dis[row];
                Y[(size_t)row * 128 + cbase + wc + lrow] = f2bf(va[reg] * dv);
                Y[(size_t)row * 128 + cbase + wc + 16 + lrow] = f2bf(vb[reg] * dv);
            }
        }
    }
}

// ---------------- final GEMM: out[G,256] = P[G,128] @ W3 + b3 (empty-graph guard) ----------------
__global__ __launch_bounds__(256) void k_gemm_final(const float* __restrict__ X,
                                                    const float* __restrict__ W,
                                                    const float* __restrict__ bias,
                                                    const int* __restrict__ goff,
                                                    float* __restrict__ out, int G) {
    __shared__ float xt[128][64];
    __shared__ float wt[128][64];
    const int t = threadIdx.x;
    const int rbase = blockIdx.x * 64;
    const int cbase = blockIdx.y * 64;

    for (int it = 0; it < 8; it++) {
        int idx = t + it * 256;
        int k4 = idx >> 6;
        int r = idx & 63;
        int row = rbase + r;
        float4 v = make_float4(0.f, 0.f, 0.f, 0.f);
        if (row < G) v = *(const float4*)(X + (size_t)row * 128 + k4 * 4);
        xt[k4 * 4 + 0][r] = v.x;
        xt[k4 * 4 + 1][r] = v.y;
        xt[k4 * 4 + 2][r] = v.z;
        xt[k4 * 4 + 3][r] = v.w;
    }
    for (int it = 0; it < 8; it++) {
        int idx = t + it * 256;
        int k = idx >> 4;
        int c4 = (idx & 15) * 4;
        *(float4*)&wt[k][c4] = *(const float4*)(W + (size_t)k * 256 + cbase + c4);
    }
    __syncthreads();

    const int r0 = (t >> 4) * 4;
    const int c0 = (t & 15) * 4;
    float acc[4][4];
#pragma unroll
    for (int i = 0; i < 4; i++)
#pragma unroll
        for (int j = 0; j < 4; j++) acc[i][j] = 0.0f;

#pragma unroll 4
    for (int k = 0; k < 128; k++) {
        float4 a = *(const float4*)&xt[k][r0];
        float4 b = *(const float4*)&wt[k][c0];
        const float av[4] = {a.x, a.y, a.z, a.w};
        const float bv[4] = {b.x, b.y, b.z, b.w};
#pragma unroll
        for (int i = 0; i < 4; i++)
#pragma unroll
            for (int j = 0; j < 4; j++) acc[i][j] += av[i] * bv[j];
    }

#pragma unroll
    for (int i = 0; i < 4; i++) {
        int row = rbase + r0 + i;
        if (row < G) {
            bool empty = (goff[row + 1] == goff[row]);
            float4 o;
            o.x = empty ? 0.f : acc[i][0] + bias[cbase + c0 + 0];
            o.y = empty ? 0.f : acc[i][1] + bias[cbase + c0 + 1];
            o.z = empty ? 0.f : acc[i][2] + bias[cbase + c0 + 2];
            o.w = empty ? 0.f : acc[i][3] + bias[cbase + c0 + 3];
            *(float4*)(out + (size_t)row * 256 + cbase + c0) = o;
        }
    }
}

// ---------------- gather body shared by aggregation kernels ----------------
__device__ __forceinline__ void gather_row(const unsigned short* __restrict__ H,
                                           const int* __restrict__ esrc,
                                           int rs, int re, int n, int c8,
                                           float (&acc)[8]) {
    constexpr int M = 128;
#pragma unroll
    for (int j = 0; j < 8; j++) acc[j] = 0.0f;
    int e = rs;
    for (; e + 8 <= re; e += 8) {
        int sid[8];
#pragma unroll
        for (int q = 0; q < 8; q++) sid[q] = esrc[e + q];
        int4 hv[8];
#pragma unroll
        for (int q = 0; q < 8; q++)
            hv[q] = *(const int4*)(H + (size_t)sid[q] * M + c8);
#pragma unroll
        for (int q = 0; q < 8; q++) {
            const int w[4] = {hv[q].x, hv[q].y, hv[q].z, hv[q].w};
#pragma unroll
            for (int k = 0; k < 4; k++) {
                acc[2 * k + 0] += lo16(w[k]);
                acc[2 * k + 1] += hi16(w[k]);
            }
        }
    }
    if (e + 4 <= re) {
        int sid[4];
#pragma unroll
        for (int q = 0; q < 4; q++) sid[q] = esrc[e + q];
        int4 hv[4];
#pragma unroll
        for (int q = 0; q < 4; q++)
            hv[q] = *(const int4*)(H + (size_t)sid[q] * M + c8);
#pragma unroll
        for (int q = 0; q < 4; q++) {
            const int w[4] = {hv[q].x, hv[q].y, hv[q].z, hv[q].w};
#pragma unroll
            for (int k = 0; k < 4; k++) {
                acc[2 * k + 0] += lo16(w[k]);
                acc[2 * k + 1] += hi16(w[k]);
            }
        }
        e += 4;
    }
    for (; e < re; e++) {
        const int s = esrc[e];
        const int4 h = *(const int4*)(H + (size_t)s * M + c8);
        const int w[4] = {h.x, h.y, h.z, h.w};
#pragma unroll
        for (int k = 0; k < 4; k++) {
            acc[2 * k + 0] += lo16(w[k]);
            acc[2 * k + 1] += hi16(w[k]);
        }
    }
    {   // self term
        const int4 h = *(const int4*)(H + (size_t)n * M + c8);
        const int w[4] = {h.x, h.y, h.z, h.w};
#pragma unroll
        for (int k = 0; k < 4; k++) {
            acc[2 * k + 0] += lo16(w[k]);
            acc[2 * k + 1] += hi16(w[k]);
        }
    }
}

// ---------------- CSR aggregation -> bf16 out, fused f32 BN stats ----------------
__global__ __launch_bounds__(256) void k_aggr2(const unsigned short* __restrict__ H,
                                               const int* __restrict__ esrc,
                                               const int* __restrict__ roff,
                                               const float* __restrict__ dis,
                                               const float* __restrict__ bias,
                                               unsigned short* __restrict__ out, int N,
                                               float* __restrict__ partial) {
    constexpr int M = 128;
    constexpr int GSZ = 16;
    constexpr int GPB = 16;
    const int nGroups = gridDim.x * GPB;
    const int gid = blockIdx.x * GPB + threadIdx.x / GSZ;
    const int lane = threadIdx.x % GSZ;
    const int c8 = lane * 8;
    const float4 bva = *(const float4*)(bias + c8);
    const float4 bvb = *(const float4*)(bias + c8 + 4);

    float ss[8], sq[8];
#pragma unroll
    for (int k = 0; k < 8; k++) { ss[k] = 0.f; sq[k] = 0.f; }

    for (int n = gid; n < N; n += nGroups) {
        float acc[8];
        gather_row(H, esrc, roff[n], roff[n + 1], n, c8, acc);
        const float dn = dis[n];
        float ov[8];
#pragma unroll
        for (int k = 0; k < 8; k++) {
            float b = (k < 4) ? (&bva.x)[k] : (&bvb.x)[k - 4];
            ov[k] = acc[k] * dn + b;
            ss[k] += ov[k];
            sq[k] += ov[k] * ov[k];
        }
        int4 o;
        o.x = pack2bf(ov[0], ov[1]);
        o.y = pack2bf(ov[2], ov[3]);
        o.z = pack2bf(ov[4], ov[5]);
        o.w = pack2bf(ov[6], ov[7]);
        *(int4*)(out + (size_t)n * M + c8) = o;
    }

    __shared__ float ls[GPB][256];
    const int g = threadIdx.x / GSZ;
#pragma unroll
    for (int k = 0; k < 8; k++) {
        ls[g][c8 + k] = ss[k];
        ls[g][128 + c8 + k] = sq[k];
    }
    __syncthreads();
    const int f = threadIdx.x;
    float v = 0.f;
#pragma unroll
    for (int gg = 0; gg < GPB; gg++) v += ls[gg][f];
    partial[(size_t)blockIdx.x * 256 + f] = v;
}

// ---------------- layer-3: aggregation + mean pool fused (block per graph) ----------------
__global__ __launch_bounds__(256) void k_aggr_pool(const unsigned short* __restrict__ H,
                                                   const int* __restrict__ esrc,
                                                   const int* __restrict__ roff,
                                                   const float* __restrict__ dis,
                                                   const int* __restrict__ goff,
                                                   float* __restrict__ P) {
    const int gr = blockIdx.x;
    const int t = threadIdx.x;
    const int grp = t >> 4;      // 16 groups
    const int lane = t & 15;
    const int c8 = lane * 8;
    const int s = goff[gr], e = goff[gr + 1];

    float pool[8];
#pragma unroll
    for (int k = 0; k < 8; k++) pool[k] = 0.f;

    for (int n = s + grp; n < e; n += 16) {
        float acc[8];
        gather_row(H, esrc, roff[n], roff[n + 1], n, c8, acc);
        const float dn = dis[n];
#pragma unroll
        for (int k = 0; k < 8; k++) pool[k] += acc[k] * dn;
    }

    __shared__ float ls[16][128];
#pragma unroll
    for (int k = 0; k < 8; k++) ls[grp][c8 + k] = pool[k];
    __syncthreads();
    if (t < 128) {
        float v = 0.f;
#pragma unroll
        for (int gg = 0; gg < 16; gg++) v += ls[gg][t];
        P[(size_t)gr * 128 + t] = v / fmaxf((float)(e - s), 1.0f);
    }
}

// ---------------- reduce partial stats ----------------
__global__ __launch_bounds__(256) void k_redstats(const float* __restrict__ partial,
                                                  float* __restrict__ sums,
                                                  float* __restrict__ sumsq, int nblk) {
    const int f = blockIdx.x;
    const int t = threadIdx.x;
    float v = 0.f;
    for (int b = t; b < nblk; b += 256) v += partial[(size_t)b * 256 + f];
    __shared__ float sh[256];
    sh[t] = v;
    __syncthreads();
    for (int d = 128; d > 0; d >>= 1) {
        if (t < d) sh[t] += sh[t + d];
        __syncthreads();
    }
    if (t == 0) {
        if (f < 128) sums[f] = sh[0];
        else sumsq[f - 128] = sh[0];
    }
}

// ---------------- BN+ReLU -> bf16 cast (bf16 in), pre-scaled by dis ----------------
__global__ void k_bncast(const unsigned short* __restrict__ X,
                         const float* __restrict__ sums,
                         const float* __restrict__ sumsq, const float* __restrict__ g,
                         const float* __restrict__ be, const float* __restrict__ dis,
                         unsigned short* __restrict__ Y, long long total8, float inv_n) {
    long long idx = (long long)blockIdx.x * blockDim.x + threadIdx.x;
    if (idx >= total8) return;
    int c8 = ((int)idx & 15) << 3;
    const float dn = dis[(int)(idx >> 4)];
    int4 v = *(const int4*)(X + idx * 8);
    const int w[4] = {v.x, v.y, v.z, v.w};
    float o[8];
#pragma unroll
    for (int k = 0; k < 4; k++) {
        o[2 * k + 0] = lo16(w[k]);
        o[2 * k + 1] = hi16(w[k]);
    }
#pragma unroll
    for (int j = 0; j < 8; j++) {
        int c = c8 + j;
        float mean = sums[c] * inv_n;
        float var = sumsq[c] * inv_n - mean * mean;
        float sc = rsqrtf(var + BN_EPS) * g[c];
        o[j] = fmaxf((o[j] - mean) * sc + be[c], 0.0f) * dn;
    }
    int4 r;
    r.x = pack2bf(o[0], o[1]);
    r.y = pack2bf(o[2], o[3]);
    r.z = pack2bf(o[4], o[5]);
    r.w = pack2bf(o[6], o[7]);
    *(int4*)(Y + idx * 8) = r;
}

extern "C" void kernel_launch(void* const* d_in, const int* in_sizes, int n_in,
                              void* d_out, int out_size, void* d_ws, size_t ws_size,
                              hipStream_t stream) {
    const float* x     = (const float*)d_in[0];
    const int*   ei    = (const int*)d_in[1];
    const int*   batch = (const int*)d_in[2];
    const float* W1 = (const float*)d_in[3];
    const float* b1 = (const float*)d_in[4];
    const float* W2 = (const float*)d_in[5];
    const float* b2 = (const float*)d_in[6];
    const float* W3 = (const float*)d_in[7];
    const float* b3 = (const float*)d_in[8];
    const float* g1 = (const float*)d_in[9];
    const float* be1 = (const float*)d_in[10];
    const float* g2 = (const float*)d_in[11];
    const float* be2 = (const float*)d_in[12];
    float* out = (float*)d_out;

    const int N = in_sizes[2];
    const int E = in_sizes[1] / 2;
    const int G = out_size / 256;
    const int* src = ei;
    const int* tgt = ei + E;

    char* ws = (char*)d_ws;
    auto take = [&](size_t bytes) {
        char* p = ws;
        ws += (bytes + 255) & ~(size_t)255;
        return p;
    };
    unsigned short* bufB   = (unsigned short*)take((size_t)N * 128 * 2);  // bf16 agg out
    unsigned short* bufH   = (unsigned short*)take((size_t)N * 128 * 2);  // bf16 gemm out
    float*          P      = (float*)take((size_t)G * 128 * 4);
    float*          dis    = (float*)take((size_t)N * 4);
    float*          sums   = (float*)take(512 * 4);
    float*          sumsq  = sums + 128;
    float*          partial= (float*)take((size_t)AGG_BLOCKS * 256 * 4);
    int*            roff   = (int*)take((size_t)(N + 1) * 4);
    int*            esrc   = (int*)take((size_t)E * 4);
    int*            goff   = (int*)take((size_t)(G + 1) * 4);
    int*            hcnt   = (int*)take((size_t)CB * NBP * 4);
    int*            btot   = (int*)take(NBP * 4);
    int*            bbase  = (int*)take((NBP + 1) * 4);
    int2*           pairs  = (int2*)take((size_t)E * 8);  // dedicated (bufB too small to alias now)

    const int B = 256;
    const int nbuck = cdiv(N, BUCKN);     // <= 256 for N <= 131072
    const int tile = cdiv(E, CB);

    // ---- CSR build: bucketed counting sort ----
    k_bhist<<<CB, B, 0, stream>>>(tgt, hcnt, E, tile, nbuck);
    k_bscan<<<nbuck, B, 0, stream>>>(hcnt, btot);
    k_scan_small<<<1, B, 0, stream>>>(btot, bbase, nbuck);
    k_bscatter2<<<CB, B, 0, stream>>>(src, tgt, hcnt, bbase, pairs, E, tile, nbuck);
    k_bucket_csr<<<nbuck + cdiv(N, B), B, 0, stream>>>(pairs, bbase, roff, dis, esrc,
                                                       N, nbuck, batch, goff, G);

    long long t8_128 = (long long)N * 16;
    const int nbx = cdiv(N, 64);

    // ---- layer 1 ----
    k_gemm_mfma<false><<<dim3(nbx, 2), B, 0, stream>>>(x, W1, bufH, N, dis,
                                                       nullptr, nullptr, nullptr, nullptr, 0.f);
    k_aggr2<<<AGG_BLOCKS, B, 0, stream>>>(bufH, esrc, roff, dis, b1, bufB, N, partial);
    k_redstats<<<256, B, 0, stream>>>(partial, sums, sumsq, AGG_BLOCKS);

    // ---- layer 2 (BN1 fused into MFMA staging, bf16 input) ----
    k_gemm_mfma<true><<<dim3(nbx, 2), B, 0, stream>>>(bufB, W2, bufH, N, dis,
                                                      sums, sumsq, g1, be1, 1.0f / N);
    k_aggr2<<<AGG_BLOCKS, B, 0, stream>>>(bufH, esrc, roff, dis, b2, bufB, N, partial);
    k_redstats<<<256, B, 0, stream>>>(partial, sums, sumsq, AGG_BLOCKS);

    // ---- layer 3: BN2+ReLU+dis cast -> fused aggregate+pool -> small GEMM ----
    k_bncast<<<cdiv(t8_128, B), B, 0, stream>>>(bufB, sums, sumsq, g2, be2, dis, bufH,
                                                t8_128, 1.0f / N);
    k_aggr_pool<<<G, B, 0, stream>>>(bufH, esrc, roff, dis, goff, P);
    k_gemm_final<<<dim3(cdiv(G, 64), 4), B, 0, stream>>>(P, W3, b3, goff, out, G);
}